// Round 9
// baseline (517.603 us; speedup 1.0000x reference)
//
#include <hip/hip_runtime.h>
#include <hip/hip_bf16.h>

// GraphVertEdgeNet on MI355X. B=64, N=64, VF=32, EF=16, DV=DE=128, LN=4.
// e stored bf16 in ws (64MB), transposed layout e_t[b][j][i][c] (contiguous
// 32KB per edge block). Inner edge kernel FUSES the v-pass (concat matmul +
// residual + BN stats) using batched W loads (16 in flight) -- R4's version
// regressed because of the serial W-load chain; this fixes it. pve never
// leaves LDS for inner layers. 12 dispatches total.

typedef __bf16 bf16_t;
typedef __bf16 bf16x8 __attribute__((ext_vector_type(8)));
typedef __bf16 bf16x4 __attribute__((ext_vector_type(4)));
typedef float f32x4 __attribute__((ext_vector_type(4)));

// Barrier that does NOT drain vmcnt: safe when cross-wave deps are LDS-only.
__device__ __forceinline__ void bar_lgkm() {
  asm volatile("s_waitcnt lgkmcnt(0)\n\ts_barrier" ::: "memory");
}

// ---------------- prep: input BN (64 blocks, LDS-reduced), Wt transpose, zero stats ----------------
__global__ __launch_bounds__(256) void k_prep(const float* __restrict__ vin,
    const float* __restrict__ g, const float* __restrict__ bt,
    const float* __restrict__ eW, float* __restrict__ v0,
    bf16_t* __restrict__ Wt, float* __restrict__ stats) {
  __shared__ float red[8][32][2];
  __shared__ float scb[32], shb[32];
  const int blk = blockIdx.x, tid = threadIdx.x;
  if (blk < 64) {  // BatchNorm1d(N*VF): 32 channels per block, 8 b per thread
    const int chq = tid & 31, bq = tid >> 5;
    const int ch = blk * 32 + chq;
    float s = 0.f, s2 = 0.f;
#pragma unroll
    for (int t = 0; t < 8; ++t) {
      float x = vin[(bq * 8 + t) * 2048 + ch];
      s += x; s2 += x * x;
    }
    red[bq][chq][0] = s;
    red[bq][chq][1] = s2;
    __syncthreads();
    if (tid < 32) {
      float S = 0.f, S2 = 0.f;
#pragma unroll
      for (int q = 0; q < 8; ++q) { S += red[q][tid][0]; S2 += red[q][tid][1]; }
      float mu = S * (1.f / 64.f);
      float var = S2 * (1.f / 64.f) - mu * mu;  // biased var
      float sc = rsqrtf(var + 1e-5f) * g[blk * 32 + tid];
      scb[tid] = sc;
      shb[tid] = bt[blk * 32 + tid] - mu * sc;
    }
    __syncthreads();
    const float sc = scb[chq], sh = shb[chq];
#pragma unroll
    for (int t = 0; t < 8; ++t) {
      int b = bq * 8 + t;
      v0[b * 2048 + ch] = vin[b * 2048 + ch] * sc + sh;
    }
  } else if (blk < 320) {  // Wt[l][n][k] = eW[l][k][n] as bf16
    int idx = (blk - 64) * 256 + tid;  // 4*128*128 = 65536
    int l = idx >> 14, r = idx & 16383, n = r >> 7, k = r & 127;
    Wt[idx] = (bf16_t)eW[(l << 14) + (k << 7) + n];
  } else {  // zero stats (512 f32)
    for (int i = tid; i < 512; i += 256) stats[i] = 0.f;
  }
}

// ------------- ev = v_in @ W + bias : [4096,K]@[K,128]. 256 thr, 8 rows/blk -------------
template <int K>
__global__ __launch_bounds__(256) void k_ev(const float* __restrict__ v_in,
    const float* __restrict__ W, const float* __restrict__ bias,
    float* __restrict__ out) {
  __shared__ float rows_s[8][K];
  const int r0 = blockIdx.x * 8;
  const int tid = threadIdx.x;
  const int c = tid & 127, h = tid >> 7;
  for (int idx = tid; idx < 8 * K; idx += 256) {
    int rr = idx / K, kk = idx % K;
    rows_s[rr][kk] = v_in[(r0 + rr) * K + kk];
  }
  __syncthreads();
  float acc[4];
  const float bv = bias[c];
#pragma unroll
  for (int r = 0; r < 4; ++r) acc[r] = bv;
  for (int k4 = 0; k4 < K; k4 += 4) {
    float w0 = W[(k4 + 0) * 128 + c], w1 = W[(k4 + 1) * 128 + c];
    float w2 = W[(k4 + 2) * 128 + c], w3 = W[(k4 + 3) * 128 + c];
#pragma unroll
    for (int r = 0; r < 4; ++r) {
      float4 x = *(const float4*)&rows_s[h * 4 + r][k4];
      acc[r] += x.x * w0 + x.y * w1 + x.z * w2 + x.w * w3;
    }
  }
#pragma unroll
  for (int r = 0; r < 4; ++r) out[(r0 + h * 4 + r) * 128 + c] = acc[r];
}

// ------------- fused BN(prev) + ev matmul (in-place v normalize). 256 thr -------------
__global__ __launch_bounds__(256) void k_evbn(float* __restrict__ v,
    const float* __restrict__ stats, const float* __restrict__ g,
    const float* __restrict__ bt, const float* __restrict__ W,
    const float* __restrict__ bias, float* __restrict__ out) {
  __shared__ float rows_s[8][128];
  const int r0 = blockIdx.x * 8;
  const int tid = threadIdx.x;
  const int c = tid & 127, h = tid >> 7;
#pragma unroll
  for (int u = 0; u < 4; ++u) {
    int idx = u * 256 + tid;
    int rr = idx >> 7, k = idx & 127;
    int n = (r0 + rr) & 63;
    float mu = stats[n] * (1.f / 8192.f);
    float var = stats[64 + n] * (1.f / 8192.f) - mu * mu;
    float sc = rsqrtf(var + 128.f) * g[n];
    float x = (v[(r0 + rr) * 128 + k] - mu) * sc + bt[n];
    rows_s[rr][k] = x;
    v[(r0 + rr) * 128 + k] = x;  // normalized v for residual/concat
  }
  __syncthreads();
  float acc[4];
  const float bv = bias[c];
#pragma unroll
  for (int r = 0; r < 4; ++r) acc[r] = bv;
  for (int k4 = 0; k4 < 128; k4 += 4) {
    float w0 = W[(k4 + 0) * 128 + c], w1 = W[(k4 + 1) * 128 + c];
    float w2 = W[(k4 + 2) * 128 + c], w3 = W[(k4 + 3) * 128 + c];
#pragma unroll
    for (int r = 0; r < 4; ++r) {
      float4 x = *(const float4*)&rows_s[h * 4 + r][k4];
      acc[r] += x.x * w0 + x.y * w1 + x.z * w2 + x.w * w3;
    }
  }
#pragma unroll
  for (int r = 0; r < 4; ++r) out[(r0 + h * 4 + r) * 128 + c] = acc[r];
}

// ------------- g1 edge pass (MFMA, K 16->32 zero-pad, 2 j/block) -------------
__global__ __launch_bounds__(256) void k_edge_g1(const float* __restrict__ e0,
    const float* __restrict__ eW, const float* __restrict__ eb,
    const float* __restrict__ ev, bf16_t* __restrict__ e_ws,
    float* __restrict__ pve) {
  __shared__ bf16_t A0s[2][64][40];
  __shared__ bf16_t Os[2][64][136];
  const int b = blockIdx.x >> 5, j0 = (blockIdx.x & 31) * 2;
  const int tid = threadIdx.x;
  const int lane = tid & 63, w = tid >> 6;
  const int quad = lane >> 4, l16 = lane & 15;
#pragma unroll
  for (int t = 0; t < 2; ++t) {
    int idx = tid + t * 256;
    int row = idx >> 3, off = (idx & 7) * 4;
    int jc = off >> 4, k = off & 15;
    f32x4 x = *(const f32x4*)&e0[((b * 64 + row) * 64 + j0) * 16 + off];
    bf16x4 y;
#pragma unroll
    for (int r = 0; r < 4; ++r) y[r] = (bf16_t)x[r];
    *(bf16x4*)&A0s[jc][row][k] = y;
    bf16x4 z = {(bf16_t)0.f, (bf16_t)0.f, (bf16_t)0.f, (bf16_t)0.f};
    *(bf16x4*)&A0s[jc][row][16 + k] = z;
  }
  const int c0[2] = {w * 32 + quad * 4, w * 32 + 16 + quad * 4};
  bf16x8 wf[2];
#pragma unroll
  for (int nt = 0; nt < 2; ++nt) {
    const int c = w * 32 + nt * 16 + l16;
#pragma unroll
    for (int jj = 0; jj < 8; ++jj)
      wf[nt][jj] = (quad < 2) ? (bf16_t)eW[(quad * 8 + jj) * 128 + c] : (bf16_t)0.f;
  }
  f32x4 acc[2][4][2];
  {
    f32x4 ebv[2], evj[2][2], evi[4][2];
#pragma unroll
    for (int nt = 0; nt < 2; ++nt) {
      ebv[nt] = *(const f32x4*)&eb[c0[nt]];
#pragma unroll
      for (int jc = 0; jc < 2; ++jc)
        evj[jc][nt] = *(const f32x4*)&ev[(b * 64 + j0 + jc) * 128 + c0[nt]];
#pragma unroll
      for (int mt = 0; mt < 4; ++mt)
        evi[mt][nt] = *(const f32x4*)&ev[(b * 64 + mt * 16 + l16) * 128 + c0[nt]];
    }
#pragma unroll
    for (int jc = 0; jc < 2; ++jc)
#pragma unroll
      for (int mt = 0; mt < 4; ++mt)
#pragma unroll
        for (int nt = 0; nt < 2; ++nt)
          acc[jc][mt][nt] = ebv[nt] + evj[jc][nt] + evi[mt][nt];
  }
  __syncthreads();
#pragma unroll
  for (int jc = 0; jc < 2; ++jc) {
#pragma unroll
    for (int mt = 0; mt < 4; ++mt) {
      bf16x8 ef = *(const bf16x8*)&A0s[jc][mt * 16 + l16][quad * 8];
#pragma unroll
      for (int nt = 0; nt < 2; ++nt)
        acc[jc][mt][nt] = __builtin_amdgcn_mfma_f32_16x16x32_bf16(wf[nt], ef, acc[jc][mt][nt], 0, 0, 0);
    }
  }
#pragma unroll
  for (int jc = 0; jc < 2; ++jc) {
#pragma unroll
    for (int nt = 0; nt < 2; ++nt) {
      f32x4 ps = {0.f, 0.f, 0.f, 0.f};
#pragma unroll
      for (int mt = 0; mt < 4; ++mt) {
        const int i = mt * 16 + l16;
        bf16x4 outv;
#pragma unroll
        for (int r = 0; r < 4; ++r) {
          float vv = fmaxf(acc[jc][mt][nt][r], 0.f);
          ps[r] += vv;
          outv[r] = (bf16_t)vv;
        }
        *(bf16x4*)&Os[jc][i][c0[nt]] = outv;
      }
#pragma unroll
      for (int m = 1; m <= 8; m <<= 1) {
#pragma unroll
        for (int r = 0; r < 4; ++r) ps[r] += __shfl_xor(ps[r], m);
      }
      if (l16 == 0) *(f32x4*)&pve[(b * 64 + j0 + jc) * 128 + c0[nt]] = ps;
    }
  }
  __syncthreads();
  {  // contiguous 32KB copy-out to transposed layout
    bf16_t* ebase = &e_ws[((size_t)(b * 64 + j0) * 64) * 128];
#pragma unroll
    for (int t = 0; t < 8; ++t) {
      int idx = tid + t * 256;
      *(int4*)&ebase[idx * 8] =
          *(const int4*)&Os[idx >> 10][(idx >> 4) & 63][(idx & 15) * 8];
    }
  }
}

// ------------- fused g1-v + layer0-ev. 256 thr, 8 rows/blk -------------
__global__ __launch_bounds__(256) void k_vg1_ev(const float* __restrict__ pve,
    const float* __restrict__ v0, const float* __restrict__ vW,
    const float* __restrict__ vb, const float* __restrict__ evW,
    const float* __restrict__ evb, float* __restrict__ v, float* __restrict__ ev) {
  __shared__ float in_s[8][160];
  __shared__ float vr[8][128];
  const int r0 = blockIdx.x * 8;
  const int tid = threadIdx.x;
  const int c = tid & 127, h = tid >> 7;
#pragma unroll
  for (int u = 0; u < 4; ++u) {
    int idx = u * 256 + tid;
    int rr = idx >> 7, k = idx & 127;
    in_s[rr][k] = pve[(r0 + rr) * 128 + k];
  }
  {
    int rr = tid >> 5, k = tid & 31;
    in_s[rr][128 + k] = v0[(r0 + rr) * 32 + k];
  }
  __syncthreads();
  float acc[4];
  const float bv = vb[c];
#pragma unroll
  for (int r = 0; r < 4; ++r) acc[r] = bv;
  for (int k4 = 0; k4 < 160; k4 += 4) {
    float w0 = vW[(k4 + 0) * 128 + c], w1 = vW[(k4 + 1) * 128 + c];
    float w2 = vW[(k4 + 2) * 128 + c], w3 = vW[(k4 + 3) * 128 + c];
#pragma unroll
    for (int r = 0; r < 4; ++r) {
      float4 x = *(const float4*)&in_s[h * 4 + r][k4];
      acc[r] += x.x * w0 + x.y * w1 + x.z * w2 + x.w * w3;
    }
  }
#pragma unroll
  for (int r = 0; r < 4; ++r) {
    float val = fmaxf(acc[r], 0.f);
    vr[h * 4 + r][c] = val;
    v[(r0 + h * 4 + r) * 128 + c] = val;
  }
  __syncthreads();
  float acc2[4];
  const float bv2 = evb[c];
#pragma unroll
  for (int r = 0; r < 4; ++r) acc2[r] = bv2;
  for (int k4 = 0; k4 < 128; k4 += 4) {
    float w0 = evW[(k4 + 0) * 128 + c], w1 = evW[(k4 + 1) * 128 + c];
    float w2 = evW[(k4 + 2) * 128 + c], w3 = evW[(k4 + 3) * 128 + c];
#pragma unroll
    for (int r = 0; r < 4; ++r) {
      float4 x = *(const float4*)&vr[h * 4 + r][k4];
      acc2[r] += x.x * w0 + x.y * w1 + x.z * w2 + x.w * w3;
    }
  }
#pragma unroll
  for (int r = 0; r < 4; ++r) ev[(r0 + h * 4 + r) * 128 + c] = acc2[r];
}

// ------------- inner edge pass + FUSED v-pass: 2048 blocks x 2 cols -------------
// e_t layout: block (b,j0) reads/writes one contiguous 32KB region.
// e += relu(e@W + eb + ev_i + ev_j); pve kept in LDS; then
// v = relu(concat(pve,v)@vW + vb) + v with batched W loads; BN stats atomics.
// LAST: e write-back replaced by edot[b][j][i] = dot(e_new, eW3).
template <bool LAST>
__global__ __launch_bounds__(256) void k_edge_inner(bf16_t* __restrict__ e_ws,
    const bf16_t* __restrict__ Wt, const float* __restrict__ eb,
    const float* __restrict__ ev, float* __restrict__ vglob,
    const float* __restrict__ vW, const float* __restrict__ vb,
    float* __restrict__ stats, const float* __restrict__ eW3,
    float* __restrict__ edt) {
  __shared__ bf16_t As[2][64][136];   // [jc][i][c], +8 pad
  __shared__ float W3s[128];
  __shared__ float pves[2][128];
  __shared__ float vrow[2][128];
  const int b = blockIdx.x >> 5, j0 = (blockIdx.x & 31) * 2;
  const int tid = threadIdx.x;
  const int lane = tid & 63, w = tid >> 6;
  const int quad = lane >> 4, l16 = lane & 15;
  bf16_t* ebase = &e_ws[((size_t)(b * 64 + j0) * 64) * 128];
  // stage 2 e columns (contiguous 32KB) + vrow
  int4 stg[8];
#pragma unroll
  for (int t = 0; t < 8; ++t) {
    int idx = tid + t * 256;
    stg[t] = *(const int4*)&ebase[idx * 8];
  }
  vrow[tid >> 7][tid & 127] = vglob[(b * 64 + j0 + (tid >> 7)) * 128 + (tid & 127)];
  if (LAST) {
    if (tid < 128) W3s[tid] = eW3[tid];
  }
  // W A-frags in registers (L2-hot): A[m=c][k]
  bf16x8 wf[2][4];
#pragma unroll
  for (int nt = 0; nt < 2; ++nt)
#pragma unroll
    for (int ks = 0; ks < 4; ++ks)
      wf[nt][ks] = *(const bf16x8*)&Wt[(w * 32 + nt * 16 + l16) * 128 + ks * 32 + quad * 8];
  const int c0[2] = {w * 32 + quad * 4, w * 32 + 16 + quad * 4};
  // acc init = eb + ev_j + ev_i (pre-barrier loads)
  f32x4 acc[2][4][2];
  {
    f32x4 ebv[2], evj[2][2], evi[4][2];
#pragma unroll
    for (int nt = 0; nt < 2; ++nt) {
      ebv[nt] = *(const f32x4*)&eb[c0[nt]];
#pragma unroll
      for (int jc = 0; jc < 2; ++jc)
        evj[jc][nt] = *(const f32x4*)&ev[(b * 64 + j0 + jc) * 128 + c0[nt]];
#pragma unroll
      for (int mt = 0; mt < 4; ++mt)
        evi[mt][nt] = *(const f32x4*)&ev[(b * 64 + mt * 16 + l16) * 128 + c0[nt]];
    }
#pragma unroll
    for (int jc = 0; jc < 2; ++jc)
#pragma unroll
      for (int mt = 0; mt < 4; ++mt)
#pragma unroll
        for (int nt = 0; nt < 2; ++nt)
          acc[jc][mt][nt] = ebv[nt] + evj[jc][nt] + evi[mt][nt];
  }
#pragma unroll
  for (int t = 0; t < 8; ++t) {
    int idx = tid + t * 256;
    *(int4*)&As[idx >> 10][(idx >> 4) & 63][(idx & 15) * 8] = stg[t];
  }
  bar_lgkm();
  // MFMA: D[c][i] = sum_k Wt[c][k] * e[i][k]  (64 MFMA per block)
#pragma unroll
  for (int ks = 0; ks < 4; ++ks) {
    bf16x8 ef[2][4];
#pragma unroll
    for (int jc = 0; jc < 2; ++jc)
#pragma unroll
      for (int mt = 0; mt < 4; ++mt)
        ef[jc][mt] = *(const bf16x8*)&As[jc][mt * 16 + l16][ks * 32 + quad * 8];
#pragma unroll
    for (int jc = 0; jc < 2; ++jc)
#pragma unroll
      for (int mt = 0; mt < 4; ++mt)
#pragma unroll
        for (int nt = 0; nt < 2; ++nt)
          acc[jc][mt][nt] = __builtin_amdgcn_mfma_f32_16x16x32_bf16(wf[nt][ks], ef[jc][mt], acc[jc][mt][nt], 0, 0, 0);
  }
  bar_lgkm();  // all MFMA frag reads of As done (LDS-only dep)
  // epilogue: relu, pve -> LDS, residual from LDS, packed b64 writes
#pragma unroll
  for (int jc = 0; jc < 2; ++jc) {
#pragma unroll
    for (int nt = 0; nt < 2; ++nt) {
      f32x4 ps = {0.f, 0.f, 0.f, 0.f};
#pragma unroll
      for (int mt = 0; mt < 4; ++mt) {
        const int i = mt * 16 + l16;
        bf16x4 eo = *(const bf16x4*)&As[jc][i][c0[nt]];
        bf16x4 outv;
#pragma unroll
        for (int r = 0; r < 4; ++r) {
          float vv = fmaxf(acc[jc][mt][nt][r], 0.f);
          ps[r] += vv;                            // pve is pre-residual
          outv[r] = (bf16_t)(vv + (float)eo[r]);  // residual
        }
        *(bf16x4*)&As[jc][i][c0[nt]] = outv;
      }
#pragma unroll
      for (int m = 1; m <= 8; m <<= 1) {  // reduce over i (l16 lanes)
#pragma unroll
        for (int r = 0; r < 4; ++r) ps[r] += __shfl_xor(ps[r], m);
      }
      if (l16 == 0) *(f32x4*)&pves[jc][c0[nt]] = ps;
    }
  }
  bar_lgkm();  // As fully updated; pves complete (LDS-only deps)
  if (!LAST) {
    // contiguous 32KB write-back
#pragma unroll
    for (int t = 0; t < 8; ++t) {
      int idx = tid + t * 256;
      *(int4*)&ebase[idx * 8] =
          *(const int4*)&As[idx >> 10][(idx >> 4) & 63][(idx & 15) * 8];
    }
  } else {
    // edot[b][j][i] = dot(e_new[b,i,j,:], W3)
    const int i = tid >> 2, q = tid & 3;
#pragma unroll
    for (int jc = 0; jc < 2; ++jc) {
      float d = 0.f;
#pragma unroll
      for (int t = 0; t < 4; ++t) {
        bf16x8 x = *(const bf16x8*)&As[jc][i][q * 32 + t * 8];
#pragma unroll
        for (int u = 0; u < 8; ++u) d += (float)x[u] * W3s[q * 32 + t * 8 + u];
      }
      d += __shfl_xor(d, 1);
      d += __shfl_xor(d, 2);
      if (q == 0) edt[(b * 64 + j0 + jc) * 64 + i] = d;
    }
  }
  // fused v-pass: v = relu(concat(pve, v) @ vW[256,128] + vb) + v, + BN stats.
  // Batched W loads (16 in flight) break the serial L2-latency chain (R4 bug).
  {
    const int jc = tid >> 7, c = tid & 127;
    float a = vb[c];
    for (int k0 = 0; k0 < 128; k0 += 16) {  // pve half
      float wv[16];
#pragma unroll
      for (int t = 0; t < 16; ++t) wv[t] = vW[(k0 + t) * 128 + c];
      f32x4 p0 = *(const f32x4*)&pves[jc][k0];
      f32x4 p1 = *(const f32x4*)&pves[jc][k0 + 4];
      f32x4 p2 = *(const f32x4*)&pves[jc][k0 + 8];
      f32x4 p3 = *(const f32x4*)&pves[jc][k0 + 12];
#pragma unroll
      for (int u = 0; u < 4; ++u) {
        a += p0[u] * wv[u];
        a += p1[u] * wv[4 + u];
        a += p2[u] * wv[8 + u];
        a += p3[u] * wv[12 + u];
      }
    }
    for (int k0 = 0; k0 < 128; k0 += 16) {  // v half
      float wv[16];
#pragma unroll
      for (int t = 0; t < 16; ++t) wv[t] = vW[(128 + k0 + t) * 128 + c];
      f32x4 p0 = *(const f32x4*)&vrow[jc][k0];
      f32x4 p1 = *(const f32x4*)&vrow[jc][k0 + 4];
      f32x4 p2 = *(const f32x4*)&vrow[jc][k0 + 8];
      f32x4 p3 = *(const f32x4*)&vrow[jc][k0 + 12];
#pragma unroll
      for (int u = 0; u < 4; ++u) {
        a += p0[u] * wv[u];
        a += p1[u] * wv[4 + u];
        a += p2[u] * wv[8 + u];
        a += p3[u] * wv[12 + u];
      }
    }
    float val = fmaxf(a, 0.f) + vrow[jc][c];  // relu + residual
    vglob[(b * 64 + j0 + jc) * 128 + c] = val;
    float s = val, s2 = val * val;
#pragma unroll
    for (int m = 1; m < 64; m <<= 1) {  // wave reduce (wave is c-contiguous, fixed jc)
      s += __shfl_xor(s, m);
      s2 += __shfl_xor(s2, m);
    }
    if (lane == 0) {
      atomicAdd(&stats[j0 + jc], s);
      atomicAdd(&stats[64 + j0 + jc], s2);
    }
  }
}

// ------------- g3 final: per-b block. BN(v), ev3, out_e = edot+eb3+ev3_i+ev3_j,
// pve3 in LDS, out_v. One kernel, 64 blocks. -------------
__global__ __launch_bounds__(256) void k_g3(const float* __restrict__ vv,
    const float* __restrict__ stats3, const float* __restrict__ g,
    const float* __restrict__ bt, const float* __restrict__ evW3,
    const float* __restrict__ evb3, const float* __restrict__ eb3,
    const float* __restrict__ edt, const float* __restrict__ vW3,
    const float* __restrict__ vb3, float* __restrict__ out_v,
    float* __restrict__ out_e) {
  __shared__ float vbn[64][132];   // +4 pad
  __shared__ float edts[64][68];   // edt[b][j][i], +4 pad
  __shared__ float scs[64], shs[64];
  __shared__ float W3e[128];
  __shared__ float vWs[132];
  __shared__ float ev3s[64];
  __shared__ float pj[4][64];
  const int b = blockIdx.x, tid = threadIdx.x;
  if (tid < 64) {
    float mu = stats3[tid] * (1.f / 8192.f);
    float var = stats3[64 + tid] * (1.f / 8192.f) - mu * mu;
    float sc = rsqrtf(var + 128.f) * g[tid];
    scs[tid] = sc;
    shs[tid] = bt[tid] - mu * sc;
  }
  if (tid < 128) W3e[tid] = evW3[tid];
  if (tid < 129) vWs[tid] = vW3[tid];
  __syncthreads();
#pragma unroll
  for (int t = 0; t < 8; ++t) {  // stage BN(v[b])
    int idx = t * 1024 + tid * 4;
    int row = idx >> 7, cc = idx & 127;
    f32x4 x = *(const f32x4*)&vv[(b * 64 + row) * 128 + cc];
    *(f32x4*)&vbn[row][cc] = x * scs[row] + shs[row];
  }
#pragma unroll
  for (int t = 0; t < 4; ++t) {  // stage edot[b]
    int idx = t * 1024 + tid * 4;
    int j = idx >> 6, i = idx & 63;
    *(f32x4*)&edts[j][i] = *(const f32x4*)&edt[(b * 64 + j) * 64 + i];
  }
  __syncthreads();
  {  // ev3s[i] = dot(vbn[i], W3e) + evb3
    int i = tid >> 2, q = tid & 3;
    float d = 0.f;
#pragma unroll
    for (int u = 0; u < 32; ++u) d += vbn[i][q * 32 + u] * W3e[q * 32 + u];
    d += __shfl_xor(d, 1);
    d += __shfl_xor(d, 2);
    if (q == 0) ev3s[i] = d + evb3[0];
  }
  __syncthreads();
  {  // out_e + per-j partial sums
    int q = tid >> 6, j = tid & 63;
    float s = 0.f;
    const float e3 = eb3[0];
    const float evj = ev3s[j];
#pragma unroll
    for (int r = 0; r < 16; ++r) {
      int i = q * 16 + r;
      float val = edts[j][i] + e3 + ev3s[i] + evj;
      out_e[(b * 64 + i) * 64 + j] = val;
      s += val;
    }
    pj[q][j] = s;
  }
  __syncthreads();
  {  // out_v[b,n] = pve3*vW[0] + dot(vbn[n], vW[1:129]) + vb
    int n = tid >> 2, q = tid & 3;
    float d = 0.f;
#pragma unroll
    for (int u = 0; u < 32; ++u) d += vbn[n][q * 32 + u] * vWs[1 + q * 32 + u];
    d += __shfl_xor(d, 1);
    d += __shfl_xor(d, 2);
    if (q == 0) {
      float p3 = pj[0][n] + pj[1][n] + pj[2][n] + pj[3][n];
      out_v[b * 64 + n] = d + p3 * vWs[0] + vb3[0];
    }
  }
}

extern "C" void kernel_launch(void* const* d_in, const int* in_sizes, int n_in,
                              void* d_out, int out_size, void* d_ws, size_t ws_size,
                              hipStream_t stream) {
  const float* in_v    = (const float*)d_in[0];
  const float* in_e    = (const float*)d_in[1];
  const float* bn_in_g = (const float*)d_in[2];
  const float* bn_in_b = (const float*)d_in[3];
  const float* g1_evW  = (const float*)d_in[4];
  const float* g1_evb  = (const float*)d_in[5];
  const float* g1_eW   = (const float*)d_in[6];
  const float* g1_eb   = (const float*)d_in[7];
  const float* g1_vW   = (const float*)d_in[8];
  const float* g1_vb   = (const float*)d_in[9];
  const float* inn_evW = (const float*)d_in[10];
  const float* inn_evb = (const float*)d_in[11];
  const float* inn_eW  = (const float*)d_in[12];
  const float* inn_eb  = (const float*)d_in[13];
  const float* inn_vW  = (const float*)d_in[14];
  const float* inn_vb  = (const float*)d_in[15];
  const float* bn_g    = (const float*)d_in[16];
  const float* bn_b    = (const float*)d_in[17];
  const float* g3_evW  = (const float*)d_in[18];
  const float* g3_evb  = (const float*)d_in[19];
  const float* g3_eW   = (const float*)d_in[20];
  const float* g3_eb   = (const float*)d_in[21];
  const float* g3_vW   = (const float*)d_in[22];
  const float* g3_vb   = (const float*)d_in[23];

  char* ws = (char*)d_ws;
  bf16_t* e_ws = (bf16_t*)(ws);                       // 64MB : e_t[b][j][i][c] bf16
  float* v     = (float*)(ws + 67108864);             // 2MB
  float* ev    = (float*)(ws + 69206016);             // 2MB
  float* pve   = (float*)(ws + 71303168);             // 2MB (g1 only)
  float* v0    = (float*)(ws + 73400320);             // 512KB
  bf16_t* Wt   = (bf16_t*)(ws + 73924608);            // 128KB
  float* edt   = (float*)(ws + 74055680);             // 1MB : edot[b][j][i]
  float* stats = (float*)(ws + 75104256);             // 2KB (4 layers x 128 f32)

  float* out_v = (float*)d_out;          // [B,N,1] = 4096
  float* out_e = (float*)d_out + 4096;   // [B,N,N,1] = 262144

  k_prep<<<321, 256, 0, stream>>>(in_v, bn_in_g, bn_in_b, inn_eW, v0, Wt, stats);

  // ---- g1 ----
  k_ev<32><<<512, 256, 0, stream>>>(v0, g1_evW, g1_evb, ev);
  k_edge_g1<<<2048, 256, 0, stream>>>(in_e, g1_eW, g1_eb, ev, e_ws, pve);
  k_vg1_ev<<<512, 256, 0, stream>>>(pve, v0, g1_vW, g1_vb, inn_evW, inn_evb, v, ev);

  // ---- inner layers (edge + v-pass fused; evbn only for l>0) ----
  for (int l = 0; l < 4; ++l) {
    if (l > 0)
      k_evbn<<<512, 256, 0, stream>>>(v, stats + (l - 1) * 128, bn_g + (l - 1) * 64,
                                      bn_b + (l - 1) * 64, inn_evW + l * 16384,
                                      inn_evb + l * 128, ev);
    if (l < 3)
      k_edge_inner<false><<<2048, 256, 0, stream>>>(e_ws, Wt + l * 16384,
          inn_eb + l * 128, ev, v, inn_vW + l * 32768, inn_vb + l * 128,
          stats + l * 128, g3_eW, edt);
    else
      k_edge_inner<true><<<2048, 256, 0, stream>>>(e_ws, Wt + l * 16384,
          inn_eb + l * 128, ev, v, inn_vW + l * 32768, inn_vb + l * 128,
          stats + l * 128, g3_eW, edt);
  }

  // ---- g3 final (BN of layer 3 on the fly; pve3 in-block) ----
  k_g3<<<64, 256, 0, stream>>>(v, stats + 384, bn_g + 192, bn_b + 192,
                               g3_evW, g3_evb, g3_eb, edt, g3_vW, g3_vb,
                               out_v, out_e);
}

// Round 10
// 399.714 us; speedup vs baseline: 1.2949x; 1.2949x over previous
//
#include <hip/hip_runtime.h>
#include <hip/hip_bf16.h>

// GraphVertEdgeNet on MI355X. B=64, N=64, VF=32, EF=16, DV=DE=128, LN=4.
// e stored bf16 in ws (64MB), transposed layout e_t[b][j][i][c] (contiguous
// streams per edge block). Inner edge: 1 j-column per block (4096 blocks,
// LDS 17.4KB, ~80 VGPR) -> ~2x occupancy vs the 2-col version; v-pass kept
// as separate kernel (fusing it raises VGPR to 156 and halves occupancy --
// verified twice, R4+R9). Layer-3 fuses the g3 edge dot, skips e write-back.

typedef __bf16 bf16_t;
typedef __bf16 bf16x8 __attribute__((ext_vector_type(8)));
typedef __bf16 bf16x4 __attribute__((ext_vector_type(4)));
typedef float f32x4 __attribute__((ext_vector_type(4)));

// Barrier that does NOT drain vmcnt: safe when cross-wave deps are LDS-only.
__device__ __forceinline__ void bar_lgkm() {
  asm volatile("s_waitcnt lgkmcnt(0)\n\ts_barrier" ::: "memory");
}

// ---------------- prep: input BN (64 blocks, LDS-reduced), Wt transpose, zero stats ----------------
__global__ __launch_bounds__(256) void k_prep(const float* __restrict__ vin,
    const float* __restrict__ g, const float* __restrict__ bt,
    const float* __restrict__ eW, float* __restrict__ v0,
    bf16_t* __restrict__ Wt, float* __restrict__ stats) {
  __shared__ float red[8][32][2];
  __shared__ float scb[32], shb[32];
  const int blk = blockIdx.x, tid = threadIdx.x;
  if (blk < 64) {  // BatchNorm1d(N*VF): 32 channels per block, 8 b per thread
    const int chq = tid & 31, bq = tid >> 5;
    const int ch = blk * 32 + chq;
    float s = 0.f, s2 = 0.f;
#pragma unroll
    for (int t = 0; t < 8; ++t) {
      float x = vin[(bq * 8 + t) * 2048 + ch];
      s += x; s2 += x * x;
    }
    red[bq][chq][0] = s;
    red[bq][chq][1] = s2;
    __syncthreads();
    if (tid < 32) {
      float S = 0.f, S2 = 0.f;
#pragma unroll
      for (int q = 0; q < 8; ++q) { S += red[q][tid][0]; S2 += red[q][tid][1]; }
      float mu = S * (1.f / 64.f);
      float var = S2 * (1.f / 64.f) - mu * mu;  // biased var
      float sc = rsqrtf(var + 1e-5f) * g[blk * 32 + tid];
      scb[tid] = sc;
      shb[tid] = bt[blk * 32 + tid] - mu * sc;
    }
    __syncthreads();
    const float sc = scb[chq], sh = shb[chq];
#pragma unroll
    for (int t = 0; t < 8; ++t) {
      int b = bq * 8 + t;
      v0[b * 2048 + ch] = vin[b * 2048 + ch] * sc + sh;
    }
  } else if (blk < 320) {  // Wt[l][n][k] = eW[l][k][n] as bf16
    int idx = (blk - 64) * 256 + tid;  // 4*128*128 = 65536
    int l = idx >> 14, r = idx & 16383, n = r >> 7, k = r & 127;
    Wt[idx] = (bf16_t)eW[(l << 14) + (k << 7) + n];
  } else {  // zero stats (512 f32)
    for (int i = tid; i < 512; i += 256) stats[i] = 0.f;
  }
}

// ------------- ev = v_in @ W + bias : [4096,K]@[K,128]. 256 thr, 8 rows/blk -------------
template <int K>
__global__ __launch_bounds__(256) void k_ev(const float* __restrict__ v_in,
    const float* __restrict__ W, const float* __restrict__ bias,
    float* __restrict__ out) {
  __shared__ float rows_s[8][K];
  const int r0 = blockIdx.x * 8;
  const int tid = threadIdx.x;
  const int c = tid & 127, h = tid >> 7;
  for (int idx = tid; idx < 8 * K; idx += 256) {
    int rr = idx / K, kk = idx % K;
    rows_s[rr][kk] = v_in[(r0 + rr) * K + kk];
  }
  __syncthreads();
  float acc[4];
  const float bv = bias[c];
#pragma unroll
  for (int r = 0; r < 4; ++r) acc[r] = bv;
  for (int k4 = 0; k4 < K; k4 += 4) {
    float w0 = W[(k4 + 0) * 128 + c], w1 = W[(k4 + 1) * 128 + c];
    float w2 = W[(k4 + 2) * 128 + c], w3 = W[(k4 + 3) * 128 + c];
#pragma unroll
    for (int r = 0; r < 4; ++r) {
      float4 x = *(const float4*)&rows_s[h * 4 + r][k4];
      acc[r] += x.x * w0 + x.y * w1 + x.z * w2 + x.w * w3;
    }
  }
#pragma unroll
  for (int r = 0; r < 4; ++r) out[(r0 + h * 4 + r) * 128 + c] = acc[r];
}

// ------------- fused BN(prev) + ev matmul (in-place v normalize). 256 thr -------------
__global__ __launch_bounds__(256) void k_evbn(float* __restrict__ v,
    const float* __restrict__ stats, const float* __restrict__ g,
    const float* __restrict__ bt, const float* __restrict__ W,
    const float* __restrict__ bias, float* __restrict__ out) {
  __shared__ float rows_s[8][128];
  const int r0 = blockIdx.x * 8;
  const int tid = threadIdx.x;
  const int c = tid & 127, h = tid >> 7;
#pragma unroll
  for (int u = 0; u < 4; ++u) {
    int idx = u * 256 + tid;
    int rr = idx >> 7, k = idx & 127;
    int n = (r0 + rr) & 63;
    float mu = stats[n] * (1.f / 8192.f);
    float var = stats[64 + n] * (1.f / 8192.f) - mu * mu;
    float sc = rsqrtf(var + 128.f) * g[n];
    float x = (v[(r0 + rr) * 128 + k] - mu) * sc + bt[n];
    rows_s[rr][k] = x;
    v[(r0 + rr) * 128 + k] = x;  // normalized v for residual/concat
  }
  __syncthreads();
  float acc[4];
  const float bv = bias[c];
#pragma unroll
  for (int r = 0; r < 4; ++r) acc[r] = bv;
  for (int k4 = 0; k4 < 128; k4 += 4) {
    float w0 = W[(k4 + 0) * 128 + c], w1 = W[(k4 + 1) * 128 + c];
    float w2 = W[(k4 + 2) * 128 + c], w3 = W[(k4 + 3) * 128 + c];
#pragma unroll
    for (int r = 0; r < 4; ++r) {
      float4 x = *(const float4*)&rows_s[h * 4 + r][k4];
      acc[r] += x.x * w0 + x.y * w1 + x.z * w2 + x.w * w3;
    }
  }
#pragma unroll
  for (int r = 0; r < 4; ++r) out[(r0 + h * 4 + r) * 128 + c] = acc[r];
}

// ------------- g1 edge pass (MFMA, K 16->32 zero-pad, 2 j/block) -------------
__global__ __launch_bounds__(256) void k_edge_g1(const float* __restrict__ e0,
    const float* __restrict__ eW, const float* __restrict__ eb,
    const float* __restrict__ ev, bf16_t* __restrict__ e_ws,
    float* __restrict__ pve) {
  __shared__ bf16_t A0s[2][64][40];
  __shared__ bf16_t Os[2][64][136];
  const int b = blockIdx.x >> 5, j0 = (blockIdx.x & 31) * 2;
  const int tid = threadIdx.x;
  const int lane = tid & 63, w = tid >> 6;
  const int quad = lane >> 4, l16 = lane & 15;
#pragma unroll
  for (int t = 0; t < 2; ++t) {
    int idx = tid + t * 256;
    int row = idx >> 3, off = (idx & 7) * 4;
    int jc = off >> 4, k = off & 15;
    f32x4 x = *(const f32x4*)&e0[((b * 64 + row) * 64 + j0) * 16 + off];
    bf16x4 y;
#pragma unroll
    for (int r = 0; r < 4; ++r) y[r] = (bf16_t)x[r];
    *(bf16x4*)&A0s[jc][row][k] = y;
    bf16x4 z = {(bf16_t)0.f, (bf16_t)0.f, (bf16_t)0.f, (bf16_t)0.f};
    *(bf16x4*)&A0s[jc][row][16 + k] = z;
  }
  const int c0[2] = {w * 32 + quad * 4, w * 32 + 16 + quad * 4};
  bf16x8 wf[2];
#pragma unroll
  for (int nt = 0; nt < 2; ++nt) {
    const int c = w * 32 + nt * 16 + l16;
#pragma unroll
    for (int jj = 0; jj < 8; ++jj)
      wf[nt][jj] = (quad < 2) ? (bf16_t)eW[(quad * 8 + jj) * 128 + c] : (bf16_t)0.f;
  }
  f32x4 acc[2][4][2];
  {
    f32x4 ebv[2], evj[2][2], evi[4][2];
#pragma unroll
    for (int nt = 0; nt < 2; ++nt) {
      ebv[nt] = *(const f32x4*)&eb[c0[nt]];
#pragma unroll
      for (int jc = 0; jc < 2; ++jc)
        evj[jc][nt] = *(const f32x4*)&ev[(b * 64 + j0 + jc) * 128 + c0[nt]];
#pragma unroll
      for (int mt = 0; mt < 4; ++mt)
        evi[mt][nt] = *(const f32x4*)&ev[(b * 64 + mt * 16 + l16) * 128 + c0[nt]];
    }
#pragma unroll
    for (int jc = 0; jc < 2; ++jc)
#pragma unroll
      for (int mt = 0; mt < 4; ++mt)
#pragma unroll
        for (int nt = 0; nt < 2; ++nt)
          acc[jc][mt][nt] = ebv[nt] + evj[jc][nt] + evi[mt][nt];
  }
  __syncthreads();
#pragma unroll
  for (int jc = 0; jc < 2; ++jc) {
#pragma unroll
    for (int mt = 0; mt < 4; ++mt) {
      bf16x8 ef = *(const bf16x8*)&A0s[jc][mt * 16 + l16][quad * 8];
#pragma unroll
      for (int nt = 0; nt < 2; ++nt)
        acc[jc][mt][nt] = __builtin_amdgcn_mfma_f32_16x16x32_bf16(wf[nt], ef, acc[jc][mt][nt], 0, 0, 0);
    }
  }
#pragma unroll
  for (int jc = 0; jc < 2; ++jc) {
#pragma unroll
    for (int nt = 0; nt < 2; ++nt) {
      f32x4 ps = {0.f, 0.f, 0.f, 0.f};
#pragma unroll
      for (int mt = 0; mt < 4; ++mt) {
        const int i = mt * 16 + l16;
        bf16x4 outv;
#pragma unroll
        for (int r = 0; r < 4; ++r) {
          float vv = fmaxf(acc[jc][mt][nt][r], 0.f);
          ps[r] += vv;
          outv[r] = (bf16_t)vv;
        }
        *(bf16x4*)&Os[jc][i][c0[nt]] = outv;
      }
#pragma unroll
      for (int m = 1; m <= 8; m <<= 1) {
#pragma unroll
        for (int r = 0; r < 4; ++r) ps[r] += __shfl_xor(ps[r], m);
      }
      if (l16 == 0) *(f32x4*)&pve[(b * 64 + j0 + jc) * 128 + c0[nt]] = ps;
    }
  }
  __syncthreads();
  {  // contiguous 32KB copy-out to transposed layout
    bf16_t* ebase = &e_ws[((size_t)(b * 64 + j0) * 64) * 128];
#pragma unroll
    for (int t = 0; t < 8; ++t) {
      int idx = tid + t * 256;
      *(int4*)&ebase[idx * 8] =
          *(const int4*)&Os[idx >> 10][(idx >> 4) & 63][(idx & 15) * 8];
    }
  }
}

// ------------- fused g1-v + layer0-ev. 256 thr, 8 rows/blk -------------
__global__ __launch_bounds__(256) void k_vg1_ev(const float* __restrict__ pve,
    const float* __restrict__ v0, const float* __restrict__ vW,
    const float* __restrict__ vb, const float* __restrict__ evW,
    const float* __restrict__ evb, float* __restrict__ v, float* __restrict__ ev) {
  __shared__ float in_s[8][160];
  __shared__ float vr[8][128];
  const int r0 = blockIdx.x * 8;
  const int tid = threadIdx.x;
  const int c = tid & 127, h = tid >> 7;
#pragma unroll
  for (int u = 0; u < 4; ++u) {
    int idx = u * 256 + tid;
    int rr = idx >> 7, k = idx & 127;
    in_s[rr][k] = pve[(r0 + rr) * 128 + k];
  }
  {
    int rr = tid >> 5, k = tid & 31;
    in_s[rr][128 + k] = v0[(r0 + rr) * 32 + k];
  }
  __syncthreads();
  float acc[4];
  const float bv = vb[c];
#pragma unroll
  for (int r = 0; r < 4; ++r) acc[r] = bv;
  for (int k4 = 0; k4 < 160; k4 += 4) {
    float w0 = vW[(k4 + 0) * 128 + c], w1 = vW[(k4 + 1) * 128 + c];
    float w2 = vW[(k4 + 2) * 128 + c], w3 = vW[(k4 + 3) * 128 + c];
#pragma unroll
    for (int r = 0; r < 4; ++r) {
      float4 x = *(const float4*)&in_s[h * 4 + r][k4];
      acc[r] += x.x * w0 + x.y * w1 + x.z * w2 + x.w * w3;
    }
  }
#pragma unroll
  for (int r = 0; r < 4; ++r) {
    float val = fmaxf(acc[r], 0.f);
    vr[h * 4 + r][c] = val;
    v[(r0 + h * 4 + r) * 128 + c] = val;
  }
  __syncthreads();
  float acc2[4];
  const float bv2 = evb[c];
#pragma unroll
  for (int r = 0; r < 4; ++r) acc2[r] = bv2;
  for (int k4 = 0; k4 < 128; k4 += 4) {
    float w0 = evW[(k4 + 0) * 128 + c], w1 = evW[(k4 + 1) * 128 + c];
    float w2 = evW[(k4 + 2) * 128 + c], w3 = evW[(k4 + 3) * 128 + c];
#pragma unroll
    for (int r = 0; r < 4; ++r) {
      float4 x = *(const float4*)&vr[h * 4 + r][k4];
      acc2[r] += x.x * w0 + x.y * w1 + x.z * w2 + x.w * w3;
    }
  }
#pragma unroll
  for (int r = 0; r < 4; ++r) ev[(r0 + h * 4 + r) * 128 + c] = acc2[r];
}

// ------------- inner edge pass: 1 j-column per block (4096 blocks) -------------
// e_t layout: block (b,j) reads/writes one contiguous 16KB region.
// e += relu(e@W + eb + ev_i + ev_j); pve = pre-residual column sums.
// LAST: e write-back replaced by edot[b][j][i] = dot(e_new, eW3).
template <bool LAST>
__global__ __launch_bounds__(256) void k_edge_inner(bf16_t* __restrict__ e_ws,
    const bf16_t* __restrict__ Wt, const float* __restrict__ eb,
    const float* __restrict__ ev, float* __restrict__ pve,
    const float* __restrict__ eW3, float* __restrict__ edt) {
  __shared__ bf16_t As[64][136];   // [i][c], +8 pad
  __shared__ float W3s[128];
  const int b = blockIdx.x >> 6, j = blockIdx.x & 63;
  const int tid = threadIdx.x;
  const int lane = tid & 63, w = tid >> 6;
  const int quad = lane >> 4, l16 = lane & 15;
  bf16_t* ebase = &e_ws[((size_t)(b * 64 + j) * 64) * 128];
  // stage 1 e column: one contiguous 16KB stream (4 int4/thread)
  int4 stg[4];
#pragma unroll
  for (int t = 0; t < 4; ++t) {
    int idx = tid + t * 256;
    stg[t] = *(const int4*)&ebase[idx * 8];
  }
  if (LAST) {
    if (tid < 128) W3s[tid] = eW3[tid];
  }
  // W A-frags in registers (L2-hot): A[m=c][k]
  bf16x8 wf[2][4];
#pragma unroll
  for (int nt = 0; nt < 2; ++nt)
#pragma unroll
    for (int ks = 0; ks < 4; ++ks)
      wf[nt][ks] = *(const bf16x8*)&Wt[(w * 32 + nt * 16 + l16) * 128 + ks * 32 + quad * 8];
  const int c0[2] = {w * 32 + quad * 4, w * 32 + 16 + quad * 4};
  // acc init = eb + ev_j + ev_i (pre-barrier loads)
  f32x4 acc[4][2];
  {
    f32x4 ebv[2], evj[2], evi[4][2];
#pragma unroll
    for (int nt = 0; nt < 2; ++nt) {
      ebv[nt] = *(const f32x4*)&eb[c0[nt]];
      evj[nt] = *(const f32x4*)&ev[(b * 64 + j) * 128 + c0[nt]];
#pragma unroll
      for (int mt = 0; mt < 4; ++mt)
        evi[mt][nt] = *(const f32x4*)&ev[(b * 64 + mt * 16 + l16) * 128 + c0[nt]];
    }
#pragma unroll
    for (int mt = 0; mt < 4; ++mt)
#pragma unroll
      for (int nt = 0; nt < 2; ++nt)
        acc[mt][nt] = ebv[nt] + evj[nt] + evi[mt][nt];
  }
#pragma unroll
  for (int t = 0; t < 4; ++t) {
    int idx = tid + t * 256;
    *(int4*)&As[idx >> 4][(idx & 15) * 8] = stg[t];
  }
  bar_lgkm();
  // MFMA: D[c][i] = sum_k Wt[c][k] * e[i][k]  (32 MFMA per wave)
#pragma unroll
  for (int ks = 0; ks < 4; ++ks) {
    bf16x8 ef[4];
#pragma unroll
    for (int mt = 0; mt < 4; ++mt)
      ef[mt] = *(const bf16x8*)&As[mt * 16 + l16][ks * 32 + quad * 8];
#pragma unroll
    for (int mt = 0; mt < 4; ++mt)
#pragma unroll
      for (int nt = 0; nt < 2; ++nt)
        acc[mt][nt] = __builtin_amdgcn_mfma_f32_16x16x32_bf16(wf[nt][ks], ef[mt], acc[mt][nt], 0, 0, 0);
  }
  bar_lgkm();  // all MFMA frag reads of As done (LDS-only dep)
  // epilogue: relu, pve, residual from LDS, packed b64 writes to own cells
#pragma unroll
  for (int nt = 0; nt < 2; ++nt) {
    f32x4 ps = {0.f, 0.f, 0.f, 0.f};
#pragma unroll
    for (int mt = 0; mt < 4; ++mt) {
      const int i = mt * 16 + l16;
      bf16x4 eo = *(const bf16x4*)&As[i][c0[nt]];
      bf16x4 outv;
#pragma unroll
      for (int r = 0; r < 4; ++r) {
        float vv = fmaxf(acc[mt][nt][r], 0.f);
        ps[r] += vv;                            // pve is pre-residual
        outv[r] = (bf16_t)(vv + (float)eo[r]);  // residual
      }
      *(bf16x4*)&As[i][c0[nt]] = outv;
    }
#pragma unroll
    for (int m = 1; m <= 8; m <<= 1) {  // reduce over i (l16 lanes)
#pragma unroll
      for (int r = 0; r < 4; ++r) ps[r] += __shfl_xor(ps[r], m);
    }
    if (l16 == 0) *(f32x4*)&pve[(b * 64 + j) * 128 + c0[nt]] = ps;
  }
  bar_lgkm();  // As fully updated (LDS-only dep)
  if (!LAST) {
    // contiguous 16KB write-back
#pragma unroll
    for (int t = 0; t < 4; ++t) {
      int idx = tid + t * 256;
      *(int4*)&ebase[idx * 8] = *(const int4*)&As[idx >> 4][(idx & 15) * 8];
    }
  } else {
    // edot[b][j][i] = dot(e_new[b,i,j,:], W3)
    const int i = tid >> 2, q = tid & 3;
    float d = 0.f;
#pragma unroll
    for (int t = 0; t < 4; ++t) {
      bf16x8 x = *(const bf16x8*)&As[i][q * 32 + t * 8];
#pragma unroll
      for (int u = 0; u < 8; ++u) d += (float)x[u] * W3s[q * 32 + t * 8 + u];
    }
    d += __shfl_xor(d, 1);
    d += __shfl_xor(d, 2);
    if (q == 0) edt[(b * 64 + j) * 64 + i] = d;
  }
}

// ------------- inner v pass: v = relu(concat(pve,v)@[256,128]+vb) + v; BN stats. 256 thr -------------
__global__ __launch_bounds__(256) void k_v_inner(const float* __restrict__ pve,
    float* __restrict__ v, const float* __restrict__ vW,
    const float* __restrict__ vb, float* __restrict__ stats) {
  __shared__ float in_s[8][256];
  __shared__ float outs[8][132];  // +4 pad
  __shared__ float part[16][2];
  const int r0 = blockIdx.x * 8;
  const int tid = threadIdx.x;
  const int c = tid & 127, h = tid >> 7;
#pragma unroll
  for (int u = 0; u < 4; ++u) {
    int idx = u * 256 + tid;
    int rr = idx >> 7, k = idx & 127;
    in_s[rr][k] = pve[(r0 + rr) * 128 + k];
    in_s[rr][128 + k] = v[(r0 + rr) * 128 + k];
  }
  __syncthreads();
  float acc[4];
  const float bv = vb[c];
#pragma unroll
  for (int r = 0; r < 4; ++r) acc[r] = bv;
  for (int k4 = 0; k4 < 256; k4 += 4) {
    float w0 = vW[(k4 + 0) * 128 + c], w1 = vW[(k4 + 1) * 128 + c];
    float w2 = vW[(k4 + 2) * 128 + c], w3 = vW[(k4 + 3) * 128 + c];
#pragma unroll
    for (int r = 0; r < 4; ++r) {
      float4 x = *(const float4*)&in_s[h * 4 + r][k4];
      acc[r] += x.x * w0 + x.y * w1 + x.z * w2 + x.w * w3;
    }
  }
#pragma unroll
  for (int r = 0; r < 4; ++r) {
    float val = fmaxf(acc[r], 0.f) + in_s[h * 4 + r][128 + c];  // relu + residual
    outs[h * 4 + r][c] = val;
    v[(r0 + h * 4 + r) * 128 + c] = val;
  }
  __syncthreads();
  if (tid < 16) {  // parallel BN-stat partial reduction
    int rr = tid >> 1, half = tid & 1;
    float s = 0.f, s2 = 0.f;
    for (int k = 0; k < 64; ++k) {
      float x = outs[rr][half * 64 + k];
      s += x; s2 += x * x;
    }
    part[tid][0] = s;
    part[tid][1] = s2;
  }
  __syncthreads();
  if (tid < 8) {
    int n = (r0 + tid) & 63;
    atomicAdd(&stats[n], part[tid * 2][0] + part[tid * 2 + 1][0]);
    atomicAdd(&stats[64 + n], part[tid * 2][1] + part[tid * 2 + 1][1]);
  }
}

// ------------- g3 final: per-b block. BN(v), ev3, out_e = edot+eb3+ev3_i+ev3_j,
// pve3 in LDS, out_v. One kernel, 64 blocks. -------------
__global__ __launch_bounds__(256) void k_g3(const float* __restrict__ vv,
    const float* __restrict__ stats3, const float* __restrict__ g,
    const float* __restrict__ bt, const float* __restrict__ evW3,
    const float* __restrict__ evb3, const float* __restrict__ eb3,
    const float* __restrict__ edt, const float* __restrict__ vW3,
    const float* __restrict__ vb3, float* __restrict__ out_v,
    float* __restrict__ out_e) {
  __shared__ float vbn[64][132];   // +4 pad
  __shared__ float edts[64][68];   // edt[b][j][i], +4 pad
  __shared__ float scs[64], shs[64];
  __shared__ float W3e[128];
  __shared__ float vWs[132];
  __shared__ float ev3s[64];
  __shared__ float pj[4][64];
  const int b = blockIdx.x, tid = threadIdx.x;
  if (tid < 64) {
    float mu = stats3[tid] * (1.f / 8192.f);
    float var = stats3[64 + tid] * (1.f / 8192.f) - mu * mu;
    float sc = rsqrtf(var + 128.f) * g[tid];
    scs[tid] = sc;
    shs[tid] = bt[tid] - mu * sc;
  }
  if (tid < 128) W3e[tid] = evW3[tid];
  if (tid < 129) vWs[tid] = vW3[tid];
  __syncthreads();
#pragma unroll
  for (int t = 0; t < 8; ++t) {  // stage BN(v[b])
    int idx = t * 1024 + tid * 4;
    int row = idx >> 7, cc = idx & 127;
    f32x4 x = *(const f32x4*)&vv[(b * 64 + row) * 128 + cc];
    *(f32x4*)&vbn[row][cc] = x * scs[row] + shs[row];
  }
#pragma unroll
  for (int t = 0; t < 4; ++t) {  // stage edot[b]
    int idx = t * 1024 + tid * 4;
    int j = idx >> 6, i = idx & 63;
    *(f32x4*)&edts[j][i] = *(const f32x4*)&edt[(b * 64 + j) * 64 + i];
  }
  __syncthreads();
  {  // ev3s[i] = dot(vbn[i], W3e) + evb3
    int i = tid >> 2, q = tid & 3;
    float d = 0.f;
#pragma unroll
    for (int u = 0; u < 32; ++u) d += vbn[i][q * 32 + u] * W3e[q * 32 + u];
    d += __shfl_xor(d, 1);
    d += __shfl_xor(d, 2);
    if (q == 0) ev3s[i] = d + evb3[0];
  }
  __syncthreads();
  {  // out_e + per-j partial sums
    int q = tid >> 6, j = tid & 63;
    float s = 0.f;
    const float e3 = eb3[0];
    const float evj = ev3s[j];
#pragma unroll
    for (int r = 0; r < 16; ++r) {
      int i = q * 16 + r;
      float val = edts[j][i] + e3 + ev3s[i] + evj;
      out_e[(b * 64 + i) * 64 + j] = val;
      s += val;
    }
    pj[q][j] = s;
  }
  __syncthreads();
  {  // out_v[b,n] = pve3*vW[0] + dot(vbn[n], vW[1:129]) + vb
    int n = tid >> 2, q = tid & 3;
    float d = 0.f;
#pragma unroll
    for (int u = 0; u < 32; ++u) d += vbn[n][q * 32 + u] * vWs[1 + q * 32 + u];
    d += __shfl_xor(d, 1);
    d += __shfl_xor(d, 2);
    if (q == 0) {
      float p3 = pj[0][n] + pj[1][n] + pj[2][n] + pj[3][n];
      out_v[b * 64 + n] = d + p3 * vWs[0] + vb3[0];
    }
  }
}

extern "C" void kernel_launch(void* const* d_in, const int* in_sizes, int n_in,
                              void* d_out, int out_size, void* d_ws, size_t ws_size,
                              hipStream_t stream) {
  const float* in_v    = (const float*)d_in[0];
  const float* in_e    = (const float*)d_in[1];
  const float* bn_in_g = (const float*)d_in[2];
  const float* bn_in_b = (const float*)d_in[3];
  const float* g1_evW  = (const float*)d_in[4];
  const float* g1_evb  = (const float*)d_in[5];
  const float* g1_eW   = (const float*)d_in[6];
  const float* g1_eb   = (const float*)d_in[7];
  const float* g1_vW   = (const float*)d_in[8];
  const float* g1_vb   = (const float*)d_in[9];
  const float* inn_evW = (const float*)d_in[10];
  const float* inn_evb = (const float*)d_in[11];
  const float* inn_eW  = (const float*)d_in[12];
  const float* inn_eb  = (const float*)d_in[13];
  const float* inn_vW  = (const float*)d_in[14];
  const float* inn_vb  = (const float*)d_in[15];
  const float* bn_g    = (const float*)d_in[16];
  const float* bn_b    = (const float*)d_in[17];
  const float* g3_evW  = (const float*)d_in[18];
  const float* g3_evb  = (const float*)d_in[19];
  const float* g3_eW   = (const float*)d_in[20];
  const float* g3_eb   = (const float*)d_in[21];
  const float* g3_vW   = (const float*)d_in[22];
  const float* g3_vb   = (const float*)d_in[23];

  char* ws = (char*)d_ws;
  bf16_t* e_ws = (bf16_t*)(ws);                       // 64MB : e_t[b][j][i][c] bf16
  float* v     = (float*)(ws + 67108864);             // 2MB
  float* ev    = (float*)(ws + 69206016);             // 2MB
  float* pve   = (float*)(ws + 71303168);             // 2MB
  float* v0    = (float*)(ws + 73400320);             // 512KB
  bf16_t* Wt   = (bf16_t*)(ws + 73924608);            // 128KB
  float* edt   = (float*)(ws + 74055680);             // 1MB : edot[b][j][i]
  float* stats = (float*)(ws + 75104256);             // 2KB (4 layers x 128 f32)

  float* out_v = (float*)d_out;          // [B,N,1] = 4096
  float* out_e = (float*)d_out + 4096;   // [B,N,N,1] = 262144

  k_prep<<<321, 256, 0, stream>>>(in_v, bn_in_g, bn_in_b, inn_eW, v0, Wt, stats);

  // ---- g1 ----
  k_ev<32><<<512, 256, 0, stream>>>(v0, g1_evW, g1_evb, ev);
  k_edge_g1<<<2048, 256, 0, stream>>>(in_e, g1_eW, g1_eb, ev, e_ws, pve);
  k_vg1_ev<<<512, 256, 0, stream>>>(pve, v0, g1_vW, g1_vb, inn_evW, inn_evb, v, ev);

  // ---- inner layers ----
  for (int l = 0; l < 4; ++l) {
    if (l > 0)
      k_evbn<<<512, 256, 0, stream>>>(v, stats + (l - 1) * 128, bn_g + (l - 1) * 64,
                                      bn_b + (l - 1) * 64, inn_evW + l * 16384,
                                      inn_evb + l * 128, ev);
    if (l < 3)
      k_edge_inner<false><<<4096, 256, 0, stream>>>(e_ws, Wt + l * 16384,
          inn_eb + l * 128, ev, pve, g3_eW, edt);
    else
      k_edge_inner<true><<<4096, 256, 0, stream>>>(e_ws, Wt + l * 16384,
          inn_eb + l * 128, ev, pve, g3_eW, edt);
    k_v_inner<<<512, 256, 0, stream>>>(pve, v, inn_vW + l * 32768, inn_vb + l * 128,
                                       stats + l * 128);
  }

  // ---- g3 final (BN of layer 3 on the fly; pve3 in-block) ----
  k_g3<<<64, 256, 0, stream>>>(v, stats + 384, bn_g + 192, bn_b + 192,
                               g3_evW, g3_evb, g3_eb, edt, g3_vW, g3_vb,
                               out_v, out_e);
}

// Round 11
// 381.612 us; speedup vs baseline: 1.3564x; 1.0474x over previous
//
#include <hip/hip_runtime.h>
#include <hip/hip_bf16.h>

// GraphVertEdgeNet on MI355X. B=64, N=64, VF=32, EF=16, DV=DE=128, LN=4.
// e stored bf16 in ws (64MB), transposed layout e_t[b][j][i][c]. Inner edge:
// 2 j-cols per block, 2048 blocks (measured-best R8 config). NEW: !LAST
// epilogue stores e_new directly to global (L2 write-combining) -> only ONE
// barrier per block (staging) instead of three; As is read-only after staging.
// v-pass separate (fusing raises VGPR 104->156, halves occupancy: R4+R9).

typedef __bf16 bf16_t;
typedef __bf16 bf16x8 __attribute__((ext_vector_type(8)));
typedef __bf16 bf16x4 __attribute__((ext_vector_type(4)));
typedef float f32x4 __attribute__((ext_vector_type(4)));

// Barrier that does NOT drain vmcnt: safe when cross-wave deps are LDS-only.
__device__ __forceinline__ void bar_lgkm() {
  asm volatile("s_waitcnt lgkmcnt(0)\n\ts_barrier" ::: "memory");
}

// ---------------- prep: input BN (64 blocks, LDS-reduced), Wt transpose, zero stats ----------------
__global__ __launch_bounds__(256) void k_prep(const float* __restrict__ vin,
    const float* __restrict__ g, const float* __restrict__ bt,
    const float* __restrict__ eW, float* __restrict__ v0,
    bf16_t* __restrict__ Wt, float* __restrict__ stats) {
  __shared__ float red[8][32][2];
  __shared__ float scb[32], shb[32];
  const int blk = blockIdx.x, tid = threadIdx.x;
  if (blk < 64) {  // BatchNorm1d(N*VF): 32 channels per block, 8 b per thread
    const int chq = tid & 31, bq = tid >> 5;
    const int ch = blk * 32 + chq;
    float s = 0.f, s2 = 0.f;
#pragma unroll
    for (int t = 0; t < 8; ++t) {
      float x = vin[(bq * 8 + t) * 2048 + ch];
      s += x; s2 += x * x;
    }
    red[bq][chq][0] = s;
    red[bq][chq][1] = s2;
    __syncthreads();
    if (tid < 32) {
      float S = 0.f, S2 = 0.f;
#pragma unroll
      for (int q = 0; q < 8; ++q) { S += red[q][tid][0]; S2 += red[q][tid][1]; }
      float mu = S * (1.f / 64.f);
      float var = S2 * (1.f / 64.f) - mu * mu;  // biased var
      float sc = rsqrtf(var + 1e-5f) * g[blk * 32 + tid];
      scb[tid] = sc;
      shb[tid] = bt[blk * 32 + tid] - mu * sc;
    }
    __syncthreads();
    const float sc = scb[chq], sh = shb[chq];
#pragma unroll
    for (int t = 0; t < 8; ++t) {
      int b = bq * 8 + t;
      v0[b * 2048 + ch] = vin[b * 2048 + ch] * sc + sh;
    }
  } else if (blk < 320) {  // Wt[l][n][k] = eW[l][k][n] as bf16
    int idx = (blk - 64) * 256 + tid;  // 4*128*128 = 65536
    int l = idx >> 14, r = idx & 16383, n = r >> 7, k = r & 127;
    Wt[idx] = (bf16_t)eW[(l << 14) + (k << 7) + n];
  } else {  // zero stats (512 f32)
    for (int i = tid; i < 512; i += 256) stats[i] = 0.f;
  }
}

// ------------- ev = v_in @ W + bias : [4096,K]@[K,128]. 256 thr, 8 rows/blk -------------
template <int K>
__global__ __launch_bounds__(256) void k_ev(const float* __restrict__ v_in,
    const float* __restrict__ W, const float* __restrict__ bias,
    float* __restrict__ out) {
  __shared__ float rows_s[8][K];
  const int r0 = blockIdx.x * 8;
  const int tid = threadIdx.x;
  const int c = tid & 127, h = tid >> 7;
  for (int idx = tid; idx < 8 * K; idx += 256) {
    int rr = idx / K, kk = idx % K;
    rows_s[rr][kk] = v_in[(r0 + rr) * K + kk];
  }
  __syncthreads();
  float acc[4];
  const float bv = bias[c];
#pragma unroll
  for (int r = 0; r < 4; ++r) acc[r] = bv;
  for (int k4 = 0; k4 < K; k4 += 4) {
    float w0 = W[(k4 + 0) * 128 + c], w1 = W[(k4 + 1) * 128 + c];
    float w2 = W[(k4 + 2) * 128 + c], w3 = W[(k4 + 3) * 128 + c];
#pragma unroll
    for (int r = 0; r < 4; ++r) {
      float4 x = *(const float4*)&rows_s[h * 4 + r][k4];
      acc[r] += x.x * w0 + x.y * w1 + x.z * w2 + x.w * w3;
    }
  }
#pragma unroll
  for (int r = 0; r < 4; ++r) out[(r0 + h * 4 + r) * 128 + c] = acc[r];
}

// ------------- fused BN(prev) + ev matmul (in-place v normalize). 256 thr -------------
__global__ __launch_bounds__(256) void k_evbn(float* __restrict__ v,
    const float* __restrict__ stats, const float* __restrict__ g,
    const float* __restrict__ bt, const float* __restrict__ W,
    const float* __restrict__ bias, float* __restrict__ out) {
  __shared__ float rows_s[8][128];
  const int r0 = blockIdx.x * 8;
  const int tid = threadIdx.x;
  const int c = tid & 127, h = tid >> 7;
#pragma unroll
  for (int u = 0; u < 4; ++u) {
    int idx = u * 256 + tid;
    int rr = idx >> 7, k = idx & 127;
    int n = (r0 + rr) & 63;
    float mu = stats[n] * (1.f / 8192.f);
    float var = stats[64 + n] * (1.f / 8192.f) - mu * mu;
    float sc = rsqrtf(var + 128.f) * g[n];
    float x = (v[(r0 + rr) * 128 + k] - mu) * sc + bt[n];
    rows_s[rr][k] = x;
    v[(r0 + rr) * 128 + k] = x;  // normalized v for residual/concat
  }
  __syncthreads();
  float acc[4];
  const float bv = bias[c];
#pragma unroll
  for (int r = 0; r < 4; ++r) acc[r] = bv;
  for (int k4 = 0; k4 < 128; k4 += 4) {
    float w0 = W[(k4 + 0) * 128 + c], w1 = W[(k4 + 1) * 128 + c];
    float w2 = W[(k4 + 2) * 128 + c], w3 = W[(k4 + 3) * 128 + c];
#pragma unroll
    for (int r = 0; r < 4; ++r) {
      float4 x = *(const float4*)&rows_s[h * 4 + r][k4];
      acc[r] += x.x * w0 + x.y * w1 + x.z * w2 + x.w * w3;
    }
  }
#pragma unroll
  for (int r = 0; r < 4; ++r) out[(r0 + h * 4 + r) * 128 + c] = acc[r];
}

// ------------- g1 edge pass (MFMA, K 16->32 zero-pad, 2 j/block) -------------
__global__ __launch_bounds__(256) void k_edge_g1(const float* __restrict__ e0,
    const float* __restrict__ eW, const float* __restrict__ eb,
    const float* __restrict__ ev, bf16_t* __restrict__ e_ws,
    float* __restrict__ pve) {
  __shared__ bf16_t A0s[2][64][40];
  __shared__ bf16_t Os[2][64][136];
  const int b = blockIdx.x >> 5, j0 = (blockIdx.x & 31) * 2;
  const int tid = threadIdx.x;
  const int lane = tid & 63, w = tid >> 6;
  const int quad = lane >> 4, l16 = lane & 15;
#pragma unroll
  for (int t = 0; t < 2; ++t) {
    int idx = tid + t * 256;
    int row = idx >> 3, off = (idx & 7) * 4;
    int jc = off >> 4, k = off & 15;
    f32x4 x = *(const f32x4*)&e0[((b * 64 + row) * 64 + j0) * 16 + off];
    bf16x4 y;
#pragma unroll
    for (int r = 0; r < 4; ++r) y[r] = (bf16_t)x[r];
    *(bf16x4*)&A0s[jc][row][k] = y;
    bf16x4 z = {(bf16_t)0.f, (bf16_t)0.f, (bf16_t)0.f, (bf16_t)0.f};
    *(bf16x4*)&A0s[jc][row][16 + k] = z;
  }
  const int c0[2] = {w * 32 + quad * 4, w * 32 + 16 + quad * 4};
  bf16x8 wf[2];
#pragma unroll
  for (int nt = 0; nt < 2; ++nt) {
    const int c = w * 32 + nt * 16 + l16;
#pragma unroll
    for (int jj = 0; jj < 8; ++jj)
      wf[nt][jj] = (quad < 2) ? (bf16_t)eW[(quad * 8 + jj) * 128 + c] : (bf16_t)0.f;
  }
  f32x4 acc[2][4][2];
  {
    f32x4 ebv[2], evj[2][2], evi[4][2];
#pragma unroll
    for (int nt = 0; nt < 2; ++nt) {
      ebv[nt] = *(const f32x4*)&eb[c0[nt]];
#pragma unroll
      for (int jc = 0; jc < 2; ++jc)
        evj[jc][nt] = *(const f32x4*)&ev[(b * 64 + j0 + jc) * 128 + c0[nt]];
#pragma unroll
      for (int mt = 0; mt < 4; ++mt)
        evi[mt][nt] = *(const f32x4*)&ev[(b * 64 + mt * 16 + l16) * 128 + c0[nt]];
    }
#pragma unroll
    for (int jc = 0; jc < 2; ++jc)
#pragma unroll
      for (int mt = 0; mt < 4; ++mt)
#pragma unroll
        for (int nt = 0; nt < 2; ++nt)
          acc[jc][mt][nt] = ebv[nt] + evj[jc][nt] + evi[mt][nt];
  }
  __syncthreads();
#pragma unroll
  for (int jc = 0; jc < 2; ++jc) {
#pragma unroll
    for (int mt = 0; mt < 4; ++mt) {
      bf16x8 ef = *(const bf16x8*)&A0s[jc][mt * 16 + l16][quad * 8];
#pragma unroll
      for (int nt = 0; nt < 2; ++nt)
        acc[jc][mt][nt] = __builtin_amdgcn_mfma_f32_16x16x32_bf16(wf[nt], ef, acc[jc][mt][nt], 0, 0, 0);
    }
  }
#pragma unroll
  for (int jc = 0; jc < 2; ++jc) {
#pragma unroll
    for (int nt = 0; nt < 2; ++nt) {
      f32x4 ps = {0.f, 0.f, 0.f, 0.f};
#pragma unroll
      for (int mt = 0; mt < 4; ++mt) {
        const int i = mt * 16 + l16;
        bf16x4 outv;
#pragma unroll
        for (int r = 0; r < 4; ++r) {
          float vv = fmaxf(acc[jc][mt][nt][r], 0.f);
          ps[r] += vv;
          outv[r] = (bf16_t)vv;
        }
        *(bf16x4*)&Os[jc][i][c0[nt]] = outv;
      }
#pragma unroll
      for (int m = 1; m <= 8; m <<= 1) {
#pragma unroll
        for (int r = 0; r < 4; ++r) ps[r] += __shfl_xor(ps[r], m);
      }
      if (l16 == 0) *(f32x4*)&pve[(b * 64 + j0 + jc) * 128 + c0[nt]] = ps;
    }
  }
  __syncthreads();
  {  // contiguous 32KB copy-out to transposed layout
    bf16_t* ebase = &e_ws[((size_t)(b * 64 + j0) * 64) * 128];
#pragma unroll
    for (int t = 0; t < 8; ++t) {
      int idx = tid + t * 256;
      *(int4*)&ebase[idx * 8] =
          *(const int4*)&Os[idx >> 10][(idx >> 4) & 63][(idx & 15) * 8];
    }
  }
}

// ------------- fused g1-v + layer0-ev. 256 thr, 8 rows/blk -------------
__global__ __launch_bounds__(256) void k_vg1_ev(const float* __restrict__ pve,
    const float* __restrict__ v0, const float* __restrict__ vW,
    const float* __restrict__ vb, const float* __restrict__ evW,
    const float* __restrict__ evb, float* __restrict__ v, float* __restrict__ ev) {
  __shared__ float in_s[8][160];
  __shared__ float vr[8][128];
  const int r0 = blockIdx.x * 8;
  const int tid = threadIdx.x;
  const int c = tid & 127, h = tid >> 7;
#pragma unroll
  for (int u = 0; u < 4; ++u) {
    int idx = u * 256 + tid;
    int rr = idx >> 7, k = idx & 127;
    in_s[rr][k] = pve[(r0 + rr) * 128 + k];
  }
  {
    int rr = tid >> 5, k = tid & 31;
    in_s[rr][128 + k] = v0[(r0 + rr) * 32 + k];
  }
  __syncthreads();
  float acc[4];
  const float bv = vb[c];
#pragma unroll
  for (int r = 0; r < 4; ++r) acc[r] = bv;
  for (int k4 = 0; k4 < 160; k4 += 4) {
    float w0 = vW[(k4 + 0) * 128 + c], w1 = vW[(k4 + 1) * 128 + c];
    float w2 = vW[(k4 + 2) * 128 + c], w3 = vW[(k4 + 3) * 128 + c];
#pragma unroll
    for (int r = 0; r < 4; ++r) {
      float4 x = *(const float4*)&in_s[h * 4 + r][k4];
      acc[r] += x.x * w0 + x.y * w1 + x.z * w2 + x.w * w3;
    }
  }
#pragma unroll
  for (int r = 0; r < 4; ++r) {
    float val = fmaxf(acc[r], 0.f);
    vr[h * 4 + r][c] = val;
    v[(r0 + h * 4 + r) * 128 + c] = val;
  }
  __syncthreads();
  float acc2[4];
  const float bv2 = evb[c];
#pragma unroll
  for (int r = 0; r < 4; ++r) acc2[r] = bv2;
  for (int k4 = 0; k4 < 128; k4 += 4) {
    float w0 = evW[(k4 + 0) * 128 + c], w1 = evW[(k4 + 1) * 128 + c];
    float w2 = evW[(k4 + 2) * 128 + c], w3 = evW[(k4 + 3) * 128 + c];
#pragma unroll
    for (int r = 0; r < 4; ++r) {
      float4 x = *(const float4*)&vr[h * 4 + r][k4];
      acc2[r] += x.x * w0 + x.y * w1 + x.z * w2 + x.w * w3;
    }
  }
#pragma unroll
  for (int r = 0; r < 4; ++r) ev[(r0 + h * 4 + r) * 128 + c] = acc2[r];
}

// ------------- inner edge pass: 2048 blocks x 2 cols, transpose layout -------------
// !LAST: single barrier; epilogue reads old e from As (read-only) and stores
// e_new DIRECTLY to global (32B chunks per row; L2 write-combines full lines).
// LAST: in-place As update + edot (needs the extra barriers).
template <bool LAST>
__global__ __launch_bounds__(256) void k_edge_inner(bf16_t* __restrict__ e_ws,
    const bf16_t* __restrict__ Wt, const float* __restrict__ eb,
    const float* __restrict__ ev, float* __restrict__ pve,
    const float* __restrict__ eW3, float* __restrict__ edt) {
  __shared__ bf16_t As[2][64][136];   // [jc][i][c], +8 pad
  __shared__ float W3s[128];
  const int b = blockIdx.x >> 5, j0 = (blockIdx.x & 31) * 2;
  const int tid = threadIdx.x;
  const int lane = tid & 63, w = tid >> 6;
  const int quad = lane >> 4, l16 = lane & 15;
  bf16_t* ebase = &e_ws[((size_t)(b * 64 + j0) * 64) * 128];
  // stage 2 e columns: one contiguous 32KB stream
  int4 stg[8];
#pragma unroll
  for (int t = 0; t < 8; ++t) {
    int idx = tid + t * 256;
    stg[t] = *(const int4*)&ebase[idx * 8];
  }
  if (LAST) {
    if (tid < 128) W3s[tid] = eW3[tid];
  }
  // W A-frags in registers (L2-hot): A[m=c][k]
  bf16x8 wf[2][4];
#pragma unroll
  for (int nt = 0; nt < 2; ++nt)
#pragma unroll
    for (int ks = 0; ks < 4; ++ks)
      wf[nt][ks] = *(const bf16x8*)&Wt[(w * 32 + nt * 16 + l16) * 128 + ks * 32 + quad * 8];
  const int c0[2] = {w * 32 + quad * 4, w * 32 + 16 + quad * 4};
  // acc init = eb + ev_j + ev_i (pre-barrier loads)
  f32x4 acc[2][4][2];
  {
    f32x4 ebv[2], evj[2][2], evi[4][2];
#pragma unroll
    for (int nt = 0; nt < 2; ++nt) {
      ebv[nt] = *(const f32x4*)&eb[c0[nt]];
#pragma unroll
      for (int jc = 0; jc < 2; ++jc)
        evj[jc][nt] = *(const f32x4*)&ev[(b * 64 + j0 + jc) * 128 + c0[nt]];
#pragma unroll
      for (int mt = 0; mt < 4; ++mt)
        evi[mt][nt] = *(const f32x4*)&ev[(b * 64 + mt * 16 + l16) * 128 + c0[nt]];
    }
#pragma unroll
    for (int jc = 0; jc < 2; ++jc)
#pragma unroll
      for (int mt = 0; mt < 4; ++mt)
#pragma unroll
        for (int nt = 0; nt < 2; ++nt)
          acc[jc][mt][nt] = ebv[nt] + evj[jc][nt] + evi[mt][nt];
  }
#pragma unroll
  for (int t = 0; t < 8; ++t) {
    int idx = tid + t * 256;
    *(int4*)&As[idx >> 10][(idx >> 4) & 63][(idx & 15) * 8] = stg[t];
  }
  bar_lgkm();
  // MFMA: D[c][i] = sum_k Wt[c][k] * e[i][k]  (64 MFMA per block)
#pragma unroll
  for (int ks = 0; ks < 4; ++ks) {
    bf16x8 ef[2][4];
#pragma unroll
    for (int jc = 0; jc < 2; ++jc)
#pragma unroll
      for (int mt = 0; mt < 4; ++mt)
        ef[jc][mt] = *(const bf16x8*)&As[jc][mt * 16 + l16][ks * 32 + quad * 8];
#pragma unroll
    for (int jc = 0; jc < 2; ++jc)
#pragma unroll
      for (int mt = 0; mt < 4; ++mt)
#pragma unroll
        for (int nt = 0; nt < 2; ++nt)
          acc[jc][mt][nt] = __builtin_amdgcn_mfma_f32_16x16x32_bf16(wf[nt][ks], ef[jc][mt], acc[jc][mt][nt], 0, 0, 0);
  }
  if (!LAST) {
    // NO barrier: As is read-only from here; e_new goes straight to global.
#pragma unroll
    for (int jc = 0; jc < 2; ++jc) {
#pragma unroll
      for (int nt = 0; nt < 2; ++nt) {
        f32x4 ps = {0.f, 0.f, 0.f, 0.f};
#pragma unroll
        for (int mt = 0; mt < 4; ++mt) {
          const int i = mt * 16 + l16;
          bf16x4 eo = *(const bf16x4*)&As[jc][i][c0[nt]];
          bf16x4 outv;
#pragma unroll
          for (int r = 0; r < 4; ++r) {
            float vv = fmaxf(acc[jc][mt][nt][r], 0.f);
            ps[r] += vv;                            // pve is pre-residual
            outv[r] = (bf16_t)(vv + (float)eo[r]);  // residual
          }
          *(bf16x4*)&ebase[jc * 8192 + i * 128 + c0[nt]] = outv;
        }
#pragma unroll
        for (int m = 1; m <= 8; m <<= 1) {  // reduce over i (l16 lanes)
#pragma unroll
          for (int r = 0; r < 4; ++r) ps[r] += __shfl_xor(ps[r], m);
        }
        if (l16 == 0) *(f32x4*)&pve[(b * 64 + j0 + jc) * 128 + c0[nt]] = ps;
      }
    }
  } else {
    bar_lgkm();  // all MFMA frag reads of As done before in-place update
#pragma unroll
    for (int jc = 0; jc < 2; ++jc) {
#pragma unroll
      for (int nt = 0; nt < 2; ++nt) {
        f32x4 ps = {0.f, 0.f, 0.f, 0.f};
#pragma unroll
        for (int mt = 0; mt < 4; ++mt) {
          const int i = mt * 16 + l16;
          bf16x4 eo = *(const bf16x4*)&As[jc][i][c0[nt]];
          bf16x4 outv;
#pragma unroll
          for (int r = 0; r < 4; ++r) {
            float vv = fmaxf(acc[jc][mt][nt][r], 0.f);
            ps[r] += vv;
            outv[r] = (bf16_t)(vv + (float)eo[r]);
          }
          *(bf16x4*)&As[jc][i][c0[nt]] = outv;
        }
#pragma unroll
        for (int m = 1; m <= 8; m <<= 1) {
#pragma unroll
          for (int r = 0; r < 4; ++r) ps[r] += __shfl_xor(ps[r], m);
        }
        if (l16 == 0) *(f32x4*)&pve[(b * 64 + j0 + jc) * 128 + c0[nt]] = ps;
      }
    }
    bar_lgkm();  // As fully updated
    // edot[b][j][i] = dot(e_new[b,i,j,:], W3)
    const int i = tid >> 2, q = tid & 3;
#pragma unroll
    for (int jc = 0; jc < 2; ++jc) {
      float d = 0.f;
#pragma unroll
      for (int t = 0; t < 4; ++t) {
        bf16x8 x = *(const bf16x8*)&As[jc][i][q * 32 + t * 8];
#pragma unroll
        for (int u = 0; u < 8; ++u) d += (float)x[u] * W3s[q * 32 + t * 8 + u];
      }
      d += __shfl_xor(d, 1);
      d += __shfl_xor(d, 2);
      if (q == 0) edt[(b * 64 + j0 + jc) * 64 + i] = d;
    }
  }
}

// ------------- inner v pass: v = relu(concat(pve,v)@[256,128]+vb) + v; BN stats. 256 thr -------------
__global__ __launch_bounds__(256) void k_v_inner(const float* __restrict__ pve,
    float* __restrict__ v, const float* __restrict__ vW,
    const float* __restrict__ vb, float* __restrict__ stats) {
  __shared__ float in_s[8][256];
  __shared__ float outs[8][132];  // +4 pad
  __shared__ float part[16][2];
  const int r0 = blockIdx.x * 8;
  const int tid = threadIdx.x;
  const int c = tid & 127, h = tid >> 7;
#pragma unroll
  for (int u = 0; u < 4; ++u) {
    int idx = u * 256 + tid;
    int rr = idx >> 7, k = idx & 127;
    in_s[rr][k] = pve[(r0 + rr) * 128 + k];
    in_s[rr][128 + k] = v[(r0 + rr) * 128 + k];
  }
  __syncthreads();
  float acc[4];
  const float bv = vb[c];
#pragma unroll
  for (int r = 0; r < 4; ++r) acc[r] = bv;
  for (int k4 = 0; k4 < 256; k4 += 4) {
    float w0 = vW[(k4 + 0) * 128 + c], w1 = vW[(k4 + 1) * 128 + c];
    float w2 = vW[(k4 + 2) * 128 + c], w3 = vW[(k4 + 3) * 128 + c];
#pragma unroll
    for (int r = 0; r < 4; ++r) {
      float4 x = *(const float4*)&in_s[h * 4 + r][k4];
      acc[r] += x.x * w0 + x.y * w1 + x.z * w2 + x.w * w3;
    }
  }
#pragma unroll
  for (int r = 0; r < 4; ++r) {
    float val = fmaxf(acc[r], 0.f) + in_s[h * 4 + r][128 + c];  // relu + residual
    outs[h * 4 + r][c] = val;
    v[(r0 + h * 4 + r) * 128 + c] = val;
  }
  __syncthreads();
  if (tid < 16) {  // parallel BN-stat partial reduction
    int rr = tid >> 1, half = tid & 1;
    float s = 0.f, s2 = 0.f;
    for (int k = 0; k < 64; ++k) {
      float x = outs[rr][half * 64 + k];
      s += x; s2 += x * x;
    }
    part[tid][0] = s;
    part[tid][1] = s2;
  }
  __syncthreads();
  if (tid < 8) {
    int n = (r0 + tid) & 63;
    atomicAdd(&stats[n], part[tid * 2][0] + part[tid * 2 + 1][0]);
    atomicAdd(&stats[64 + n], part[tid * 2][1] + part[tid * 2 + 1][1]);
  }
}

// ------------- g3 final: per-b block. BN(v), ev3, out_e = edot+eb3+ev3_i+ev3_j,
// pve3 in LDS, out_v. One kernel, 64 blocks. -------------
__global__ __launch_bounds__(256) void k_g3(const float* __restrict__ vv,
    const float* __restrict__ stats3, const float* __restrict__ g,
    const float* __restrict__ bt, const float* __restrict__ evW3,
    const float* __restrict__ evb3, const float* __restrict__ eb3,
    const float* __restrict__ edt, const float* __restrict__ vW3,
    const float* __restrict__ vb3, float* __restrict__ out_v,
    float* __restrict__ out_e) {
  __shared__ float vbn[64][132];   // +4 pad
  __shared__ float edts[64][68];   // edt[b][j][i], +4 pad
  __shared__ float scs[64], shs[64];
  __shared__ float W3e[128];
  __shared__ float vWs[132];
  __shared__ float ev3s[64];
  __shared__ float pj[4][64];
  const int b = blockIdx.x, tid = threadIdx.x;
  if (tid < 64) {
    float mu = stats3[tid] * (1.f / 8192.f);
    float var = stats3[64 + tid] * (1.f / 8192.f) - mu * mu;
    float sc = rsqrtf(var + 128.f) * g[tid];
    scs[tid] = sc;
    shs[tid] = bt[tid] - mu * sc;
  }
  if (tid < 128) W3e[tid] = evW3[tid];
  if (tid < 129) vWs[tid] = vW3[tid];
  __syncthreads();
#pragma unroll
  for (int t = 0; t < 8; ++t) {  // stage BN(v[b])
    int idx = t * 1024 + tid * 4;
    int row = idx >> 7, cc = idx & 127;
    f32x4 x = *(const f32x4*)&vv[(b * 64 + row) * 128 + cc];
    *(f32x4*)&vbn[row][cc] = x * scs[row] + shs[row];
  }
#pragma unroll
  for (int t = 0; t < 4; ++t) {  // stage edot[b]
    int idx = t * 1024 + tid * 4;
    int j = idx >> 6, i = idx & 63;
    *(f32x4*)&edts[j][i] = *(const f32x4*)&edt[(b * 64 + j) * 64 + i];
  }
  __syncthreads();
  {  // ev3s[i] = dot(vbn[i], W3e) + evb3
    int i = tid >> 2, q = tid & 3;
    float d = 0.f;
#pragma unroll
    for (int u = 0; u < 32; ++u) d += vbn[i][q * 32 + u] * W3e[q * 32 + u];
    d += __shfl_xor(d, 1);
    d += __shfl_xor(d, 2);
    if (q == 0) ev3s[i] = d + evb3[0];
  }
  __syncthreads();
  {  // out_e + per-j partial sums
    int q = tid >> 6, j = tid & 63;
    float s = 0.f;
    const float e3 = eb3[0];
    const float evj = ev3s[j];
#pragma unroll
    for (int r = 0; r < 16; ++r) {
      int i = q * 16 + r;
      float val = edts[j][i] + e3 + ev3s[i] + evj;
      out_e[(b * 64 + i) * 64 + j] = val;
      s += val;
    }
    pj[q][j] = s;
  }
  __syncthreads();
  {  // out_v[b,n] = pve3*vW[0] + dot(vbn[n], vW[1:129]) + vb
    int n = tid >> 2, q = tid & 3;
    float d = 0.f;
#pragma unroll
    for (int u = 0; u < 32; ++u) d += vbn[n][q * 32 + u] * vWs[1 + q * 32 + u];
    d += __shfl_xor(d, 1);
    d += __shfl_xor(d, 2);
    if (q == 0) {
      float p3 = pj[0][n] + pj[1][n] + pj[2][n] + pj[3][n];
      out_v[b * 64 + n] = d + p3 * vWs[0] + vb3[0];
    }
  }
}

extern "C" void kernel_launch(void* const* d_in, const int* in_sizes, int n_in,
                              void* d_out, int out_size, void* d_ws, size_t ws_size,
                              hipStream_t stream) {
  const float* in_v    = (const float*)d_in[0];
  const float* in_e    = (const float*)d_in[1];
  const float* bn_in_g = (const float*)d_in[2];
  const float* bn_in_b = (const float*)d_in[3];
  const float* g1_evW  = (const float*)d_in[4];
  const float* g1_evb  = (const float*)d_in[5];
  const float* g1_eW   = (const float*)d_in[6];
  const float* g1_eb   = (const float*)d_in[7];
  const float* g1_vW   = (const float*)d_in[8];
  const float* g1_vb   = (const float*)d_in[9];
  const float* inn_evW = (const float*)d_in[10];
  const float* inn_evb = (const float*)d_in[11];
  const float* inn_eW  = (const float*)d_in[12];
  const float* inn_eb  = (const float*)d_in[13];
  const float* inn_vW  = (const float*)d_in[14];
  const float* inn_vb  = (const float*)d_in[15];
  const float* bn_g    = (const float*)d_in[16];
  const float* bn_b    = (const float*)d_in[17];
  const float* g3_evW  = (const float*)d_in[18];
  const float* g3_evb  = (const float*)d_in[19];
  const float* g3_eW   = (const float*)d_in[20];
  const float* g3_eb   = (const float*)d_in[21];
  const float* g3_vW   = (const float*)d_in[22];
  const float* g3_vb   = (const float*)d_in[23];

  char* ws = (char*)d_ws;
  bf16_t* e_ws = (bf16_t*)(ws);                       // 64MB : e_t[b][j][i][c] bf16
  float* v     = (float*)(ws + 67108864);             // 2MB
  float* ev    = (float*)(ws + 69206016);             // 2MB
  float* pve   = (float*)(ws + 71303168);             // 2MB
  float* v0    = (float*)(ws + 73400320);             // 512KB
  bf16_t* Wt   = (bf16_t*)(ws + 73924608);            // 128KB
  float* edt   = (float*)(ws + 74055680);             // 1MB : edot[b][j][i]
  float* stats = (float*)(ws + 75104256);             // 2KB (4 layers x 128 f32)

  float* out_v = (float*)d_out;          // [B,N,1] = 4096
  float* out_e = (float*)d_out + 4096;   // [B,N,N,1] = 262144

  k_prep<<<321, 256, 0, stream>>>(in_v, bn_in_g, bn_in_b, inn_eW, v0, Wt, stats);

  // ---- g1 ----
  k_ev<32><<<512, 256, 0, stream>>>(v0, g1_evW, g1_evb, ev);
  k_edge_g1<<<2048, 256, 0, stream>>>(in_e, g1_eW, g1_eb, ev, e_ws, pve);
  k_vg1_ev<<<512, 256, 0, stream>>>(pve, v0, g1_vW, g1_vb, inn_evW, inn_evb, v, ev);

  // ---- inner layers ----
  for (int l = 0; l < 4; ++l) {
    if (l > 0)
      k_evbn<<<512, 256, 0, stream>>>(v, stats + (l - 1) * 128, bn_g + (l - 1) * 64,
                                      bn_b + (l - 1) * 64, inn_evW + l * 16384,
                                      inn_evb + l * 128, ev);
    if (l < 3)
      k_edge_inner<false><<<2048, 256, 0, stream>>>(e_ws, Wt + l * 16384,
          inn_eb + l * 128, ev, pve, g3_eW, edt);
    else
      k_edge_inner<true><<<2048, 256, 0, stream>>>(e_ws, Wt + l * 16384,
          inn_eb + l * 128, ev, pve, g3_eW, edt);
    k_v_inner<<<512, 256, 0, stream>>>(pve, v, inn_vW + l * 32768, inn_vb + l * 128,
                                       stats + l * 128);
  }

  // ---- g3 final (BN of layer 3 on the fly; pve3 in-block) ----
  k_g3<<<64, 256, 0, stream>>>(v, stats + 384, bn_g + 192, bn_b + 192,
                               g3_evW, g3_evb, g3_eb, edt, g3_vW, g3_vb,
                               out_v, out_e);
}

// Round 13
// 371.091 us; speedup vs baseline: 1.3948x; 1.0284x over previous
//
#include <hip/hip_runtime.h>
#include <hip/hip_bf16.h>

// GraphVertEdgeNet on MI355X. B=64, N=64, VF=32, EF=16, DV=DE=128, LN=4.
// e stored bf16 in ws (64MB), transposed layout e_t[b][j][i][c]. Inner edge:
// R8 measured-best config (2 j-cols/block, 2048 blocks, 3-barrier LDS
// epilogue). BN folded as per-row affine everywhere v_norm is needed:
//  - edge C-init: ev = sc_r*rawev + sh_r*colsumW + evb
//  - v-pass: concat/residual use affine(v_raw)   <-- R12's missing piece
// v buffer holds PRE-BN raw v; k_evbn kernels eliminated (13 dispatches).

typedef __bf16 bf16_t;
typedef __bf16 bf16x8 __attribute__((ext_vector_type(8)));
typedef __bf16 bf16x4 __attribute__((ext_vector_type(4)));
typedef float f32x4 __attribute__((ext_vector_type(4)));

__device__ __forceinline__ void bar_lgkm() {
  asm volatile("s_waitcnt lgkmcnt(0)\n\ts_barrier" ::: "memory");
}

// ---- prep: input BN (64 blocks), Wt transpose, zero stats, colsumW ----
__global__ __launch_bounds__(256) void k_prep(const float* __restrict__ vin,
    const float* __restrict__ g, const float* __restrict__ bt,
    const float* __restrict__ eW, const float* __restrict__ evW,
    float* __restrict__ v0, bf16_t* __restrict__ Wt,
    float* __restrict__ stats, float* __restrict__ colsum) {
  __shared__ float red[8][32][2];
  __shared__ float scb[32], shb[32];
  const int blk = blockIdx.x, tid = threadIdx.x;
  if (blk < 64) {
    const int chq = tid & 31, bq = tid >> 5;
    const int ch = blk * 32 + chq;
    float s = 0.f, s2 = 0.f;
#pragma unroll
    for (int t = 0; t < 8; ++t) {
      float x = vin[(bq * 8 + t) * 2048 + ch];
      s += x; s2 += x * x;
    }
    red[bq][chq][0] = s;
    red[bq][chq][1] = s2;
    __syncthreads();
    if (tid < 32) {
      float S = 0.f, S2 = 0.f;
#pragma unroll
      for (int q = 0; q < 8; ++q) { S += red[q][tid][0]; S2 += red[q][tid][1]; }
      float mu = S * (1.f / 64.f);
      float var = S2 * (1.f / 64.f) - mu * mu;  // biased var
      float sc = rsqrtf(var + 1e-5f) * g[blk * 32 + tid];
      scb[tid] = sc;
      shb[tid] = bt[blk * 32 + tid] - mu * sc;
    }
    __syncthreads();
    const float sc = scb[chq], sh = shb[chq];
#pragma unroll
    for (int t = 0; t < 8; ++t) {
      int b = bq * 8 + t;
      v0[b * 2048 + ch] = vin[b * 2048 + ch] * sc + sh;
    }
  } else if (blk < 320) {  // Wt[l][n][k] = eW[l][k][n] as bf16
    int idx = (blk - 64) * 256 + tid;
    int l = idx >> 14, r = idx & 16383, n = r >> 7, k = r & 127;
    Wt[idx] = (bf16_t)eW[(l << 14) + (k << 7) + n];
  } else {  // zero stats + colsum[l][c] = sum_k evW[l][k][c]
    for (int i = tid; i < 512; i += 256) stats[i] = 0.f;
#pragma unroll
    for (int t = 0; t < 2; ++t) {
      int idx = tid + t * 256;
      int l = idx >> 7, c = idx & 127;
      float s = 0.f;
      for (int k = 0; k < 128; ++k) s += evW[(l << 14) + (k << 7) + c];
      colsum[idx] = s;
    }
  }
}

// ------------- g1 ev = v0 @ W + bias : [4096,32]@[32,128]. 256 thr -------------
__global__ __launch_bounds__(256) void k_ev32(const float* __restrict__ v_in,
    const float* __restrict__ W, const float* __restrict__ bias,
    float* __restrict__ out) {
  __shared__ float rows_s[8][32];
  const int r0 = blockIdx.x * 8;
  const int tid = threadIdx.x;
  const int c = tid & 127, h = tid >> 7;
  {
    int rr = tid >> 5, kk = tid & 31;
    rows_s[rr][kk] = v_in[(r0 + rr) * 32 + kk];
  }
  __syncthreads();
  float acc[4];
  const float bv = bias[c];
#pragma unroll
  for (int r = 0; r < 4; ++r) acc[r] = bv;
  for (int k4 = 0; k4 < 32; k4 += 4) {
    float w0 = W[(k4 + 0) * 128 + c], w1 = W[(k4 + 1) * 128 + c];
    float w2 = W[(k4 + 2) * 128 + c], w3 = W[(k4 + 3) * 128 + c];
#pragma unroll
    for (int r = 0; r < 4; ++r) {
      float4 x = *(const float4*)&rows_s[h * 4 + r][k4];
      acc[r] += x.x * w0 + x.y * w1 + x.z * w2 + x.w * w3;
    }
  }
#pragma unroll
  for (int r = 0; r < 4; ++r) out[(r0 + h * 4 + r) * 128 + c] = acc[r];
}

// ------------- g1 edge pass (MFMA, K 16->32 zero-pad, 2 j/block) -------------
__global__ __launch_bounds__(256) void k_edge_g1(const float* __restrict__ e0,
    const float* __restrict__ eW, const float* __restrict__ eb,
    const float* __restrict__ ev, bf16_t* __restrict__ e_ws,
    float* __restrict__ pve) {
  __shared__ bf16_t A0s[2][64][40];
  __shared__ bf16_t Os[2][64][136];
  const int b = blockIdx.x >> 5, j0 = (blockIdx.x & 31) * 2;
  const int tid = threadIdx.x;
  const int lane = tid & 63, w = tid >> 6;
  const int quad = lane >> 4, l16 = lane & 15;
#pragma unroll
  for (int t = 0; t < 2; ++t) {
    int idx = tid + t * 256;
    int row = idx >> 3, off = (idx & 7) * 4;
    int jc = off >> 4, k = off & 15;
    f32x4 x = *(const f32x4*)&e0[((b * 64 + row) * 64 + j0) * 16 + off];
    bf16x4 y;
#pragma unroll
    for (int r = 0; r < 4; ++r) y[r] = (bf16_t)x[r];
    *(bf16x4*)&A0s[jc][row][k] = y;
    bf16x4 z = {(bf16_t)0.f, (bf16_t)0.f, (bf16_t)0.f, (bf16_t)0.f};
    *(bf16x4*)&A0s[jc][row][16 + k] = z;
  }
  const int c0[2] = {w * 32 + quad * 4, w * 32 + 16 + quad * 4};
  bf16x8 wf[2];
#pragma unroll
  for (int nt = 0; nt < 2; ++nt) {
    const int c = w * 32 + nt * 16 + l16;
#pragma unroll
    for (int jj = 0; jj < 8; ++jj)
      wf[nt][jj] = (quad < 2) ? (bf16_t)eW[(quad * 8 + jj) * 128 + c] : (bf16_t)0.f;
  }
  f32x4 acc[2][4][2];
  {
    f32x4 ebv[2], evj[2][2], evi[4][2];
#pragma unroll
    for (int nt = 0; nt < 2; ++nt) {
      ebv[nt] = *(const f32x4*)&eb[c0[nt]];
#pragma unroll
      for (int jc = 0; jc < 2; ++jc)
        evj[jc][nt] = *(const f32x4*)&ev[(b * 64 + j0 + jc) * 128 + c0[nt]];
#pragma unroll
      for (int mt = 0; mt < 4; ++mt)
        evi[mt][nt] = *(const f32x4*)&ev[(b * 64 + mt * 16 + l16) * 128 + c0[nt]];
    }
#pragma unroll
    for (int jc = 0; jc < 2; ++jc)
#pragma unroll
      for (int mt = 0; mt < 4; ++mt)
#pragma unroll
        for (int nt = 0; nt < 2; ++nt)
          acc[jc][mt][nt] = ebv[nt] + evj[jc][nt] + evi[mt][nt];
  }
  __syncthreads();
#pragma unroll
  for (int jc = 0; jc < 2; ++jc) {
#pragma unroll
    for (int mt = 0; mt < 4; ++mt) {
      bf16x8 ef = *(const bf16x8*)&A0s[jc][mt * 16 + l16][quad * 8];
#pragma unroll
      for (int nt = 0; nt < 2; ++nt)
        acc[jc][mt][nt] = __builtin_amdgcn_mfma_f32_16x16x32_bf16(wf[nt], ef, acc[jc][mt][nt], 0, 0, 0);
    }
  }
#pragma unroll
  for (int jc = 0; jc < 2; ++jc) {
#pragma unroll
    for (int nt = 0; nt < 2; ++nt) {
      f32x4 ps = {0.f, 0.f, 0.f, 0.f};
#pragma unroll
      for (int mt = 0; mt < 4; ++mt) {
        const int i = mt * 16 + l16;
        bf16x4 outv;
#pragma unroll
        for (int r = 0; r < 4; ++r) {
          float vv = fmaxf(acc[jc][mt][nt][r], 0.f);
          ps[r] += vv;
          outv[r] = (bf16_t)vv;
        }
        *(bf16x4*)&Os[jc][i][c0[nt]] = outv;
      }
#pragma unroll
      for (int m = 1; m <= 8; m <<= 1) {
#pragma unroll
        for (int r = 0; r < 4; ++r) ps[r] += __shfl_xor(ps[r], m);
      }
      if (l16 == 0) *(f32x4*)&pve[(b * 64 + j0 + jc) * 128 + c0[nt]] = ps;
    }
  }
  __syncthreads();
  {
    bf16_t* ebase = &e_ws[((size_t)(b * 64 + j0) * 64) * 128];
#pragma unroll
    for (int t = 0; t < 8; ++t) {
      int idx = tid + t * 256;
      *(int4*)&ebase[idx * 8] =
          *(const int4*)&Os[idx >> 10][(idx >> 4) & 63][(idx & 15) * 8];
    }
  }
}

// ------------- fused g1-v + layer0-rawev (rawev = v @ evW, NO bias) -------------
__global__ __launch_bounds__(256) void k_vg1_ev(const float* __restrict__ pve,
    const float* __restrict__ v0, const float* __restrict__ vW,
    const float* __restrict__ vb, const float* __restrict__ evW,
    float* __restrict__ v, float* __restrict__ ev) {
  __shared__ float in_s[8][160];
  __shared__ float vr[8][128];
  const int r0 = blockIdx.x * 8;
  const int tid = threadIdx.x;
  const int c = tid & 127, h = tid >> 7;
#pragma unroll
  for (int u = 0; u < 4; ++u) {
    int idx = u * 256 + tid;
    int rr = idx >> 7, k = idx & 127;
    in_s[rr][k] = pve[(r0 + rr) * 128 + k];
  }
  {
    int rr = tid >> 5, k = tid & 31;
    in_s[rr][128 + k] = v0[(r0 + rr) * 32 + k];
  }
  __syncthreads();
  float acc[4];
  const float bv = vb[c];
#pragma unroll
  for (int r = 0; r < 4; ++r) acc[r] = bv;
  for (int k4 = 0; k4 < 160; k4 += 4) {
    float w0 = vW[(k4 + 0) * 128 + c], w1 = vW[(k4 + 1) * 128 + c];
    float w2 = vW[(k4 + 2) * 128 + c], w3 = vW[(k4 + 3) * 128 + c];
#pragma unroll
    for (int r = 0; r < 4; ++r) {
      float4 x = *(const float4*)&in_s[h * 4 + r][k4];
      acc[r] += x.x * w0 + x.y * w1 + x.z * w2 + x.w * w3;
    }
  }
#pragma unroll
  for (int r = 0; r < 4; ++r) {
    float val = fmaxf(acc[r], 0.f);
    vr[h * 4 + r][c] = val;
    v[(r0 + h * 4 + r) * 128 + c] = val;
  }
  __syncthreads();
  float acc2[4] = {0.f, 0.f, 0.f, 0.f};  // rawev: no bias (edge adds evb)
  for (int k4 = 0; k4 < 128; k4 += 4) {
    float w0 = evW[(k4 + 0) * 128 + c], w1 = evW[(k4 + 1) * 128 + c];
    float w2 = evW[(k4 + 2) * 128 + c], w3 = evW[(k4 + 3) * 128 + c];
#pragma unroll
    for (int r = 0; r < 4; ++r) {
      float4 x = *(const float4*)&vr[h * 4 + r][k4];
      acc2[r] += x.x * w0 + x.y * w1 + x.z * w2 + x.w * w3;
    }
  }
#pragma unroll
  for (int r = 0; r < 4; ++r) ev[(r0 + h * 4 + r) * 128 + c] = acc2[r];
}

// ------------- inner edge pass: R8 config + BN-fold at C-init -------------
template <bool LAST>
__global__ __launch_bounds__(256) void k_edge_inner(bf16_t* __restrict__ e_ws,
    const bf16_t* __restrict__ Wt, const float* __restrict__ eb,
    const float* __restrict__ evb, const float* __restrict__ rawev,
    const float* __restrict__ colsum, const float* __restrict__ stats_prev,
    const float* __restrict__ g_prev, const float* __restrict__ bt_prev,
    float* __restrict__ pve, const float* __restrict__ eW3,
    float* __restrict__ edt) {
  __shared__ bf16_t As[2][64][136];   // [jc][i][c], +8 pad
  __shared__ float W3s[128];
  __shared__ float scs[64], shs[64];
  const int b = blockIdx.x >> 5, j0 = (blockIdx.x & 31) * 2;
  const int tid = threadIdx.x;
  const int lane = tid & 63, w = tid >> 6;
  const int quad = lane >> 4, l16 = lane & 15;
  bf16_t* ebase = &e_ws[((size_t)(b * 64 + j0) * 64) * 128];
  if (tid < 64) {  // per-row BN affine (identity for layer 0)
    if (stats_prev) {
      float mu = stats_prev[tid] * (1.f / 8192.f);
      float var = stats_prev[64 + tid] * (1.f / 8192.f) - mu * mu;
      float sc = rsqrtf(var + 128.f) * g_prev[tid];
      scs[tid] = sc;
      shs[tid] = bt_prev[tid] - mu * sc;
    } else {
      scs[tid] = 1.f;
      shs[tid] = 0.f;
    }
  }
  int4 stg[8];
#pragma unroll
  for (int t = 0; t < 8; ++t) {
    int idx = tid + t * 256;
    stg[t] = *(const int4*)&ebase[idx * 8];
  }
  if (LAST) {
    if (tid < 128) W3s[tid] = eW3[tid];
  }
  bf16x8 wf[2][4];
#pragma unroll
  for (int nt = 0; nt < 2; ++nt)
#pragma unroll
    for (int ks = 0; ks < 4; ++ks)
      wf[nt][ks] = *(const bf16x8*)&Wt[(w * 32 + nt * 16 + l16) * 128 + ks * 32 + quad * 8];
  const int c0[2] = {w * 32 + quad * 4, w * 32 + 16 + quad * 4};
  f32x4 basev[2], cs[2], evj[2][2], evi[4][2];
#pragma unroll
  for (int nt = 0; nt < 2; ++nt) {
    f32x4 e1 = *(const f32x4*)&eb[c0[nt]];
    f32x4 e2 = *(const f32x4*)&evb[c0[nt]];
    basev[nt] = e1 + 2.f * e2;
    cs[nt] = *(const f32x4*)&colsum[c0[nt]];
#pragma unroll
    for (int jc = 0; jc < 2; ++jc)
      evj[jc][nt] = *(const f32x4*)&rawev[(b * 64 + j0 + jc) * 128 + c0[nt]];
#pragma unroll
    for (int mt = 0; mt < 4; ++mt)
      evi[mt][nt] = *(const f32x4*)&rawev[(b * 64 + mt * 16 + l16) * 128 + c0[nt]];
  }
#pragma unroll
  for (int t = 0; t < 8; ++t) {
    int idx = tid + t * 256;
    *(int4*)&As[idx >> 10][(idx >> 4) & 63][(idx & 15) * 8] = stg[t];
  }
  bar_lgkm();  // staging done; scs/shs visible
  f32x4 acc[2][4][2];
  {
    float scj[2], shj[2];
#pragma unroll
    for (int jc = 0; jc < 2; ++jc) { scj[jc] = scs[j0 + jc]; shj[jc] = shs[j0 + jc]; }
#pragma unroll
    for (int mt = 0; mt < 4; ++mt) {
      const int i = mt * 16 + l16;
      const float sci = scs[i], shi = shs[i];
#pragma unroll
      for (int jc = 0; jc < 2; ++jc) {
        const float shsum = shi + shj[jc];
#pragma unroll
        for (int nt = 0; nt < 2; ++nt)
          acc[jc][mt][nt] = basev[nt] + shsum * cs[nt] + scj[jc] * evj[jc][nt] + sci * evi[mt][nt];
      }
    }
  }
#pragma unroll
  for (int ks = 0; ks < 4; ++ks) {
    bf16x8 ef[2][4];
#pragma unroll
    for (int jc = 0; jc < 2; ++jc)
#pragma unroll
      for (int mt = 0; mt < 4; ++mt)
        ef[jc][mt] = *(const bf16x8*)&As[jc][mt * 16 + l16][ks * 32 + quad * 8];
#pragma unroll
    for (int jc = 0; jc < 2; ++jc)
#pragma unroll
      for (int mt = 0; mt < 4; ++mt)
#pragma unroll
        for (int nt = 0; nt < 2; ++nt)
          acc[jc][mt][nt] = __builtin_amdgcn_mfma_f32_16x16x32_bf16(wf[nt][ks], ef[jc][mt], acc[jc][mt][nt], 0, 0, 0);
  }
  bar_lgkm();
#pragma unroll
  for (int jc = 0; jc < 2; ++jc) {
#pragma unroll
    for (int nt = 0; nt < 2; ++nt) {
      f32x4 ps = {0.f, 0.f, 0.f, 0.f};
#pragma unroll
      for (int mt = 0; mt < 4; ++mt) {
        const int i = mt * 16 + l16;
        bf16x4 eo = *(const bf16x4*)&As[jc][i][c0[nt]];
        bf16x4 outv;
#pragma unroll
        for (int r = 0; r < 4; ++r) {
          float vv = fmaxf(acc[jc][mt][nt][r], 0.f);
          ps[r] += vv;                            // pve is pre-residual
          outv[r] = (bf16_t)(vv + (float)eo[r]);  // residual
        }
        *(bf16x4*)&As[jc][i][c0[nt]] = outv;
      }
#pragma unroll
      for (int m = 1; m <= 8; m <<= 1) {
#pragma unroll
        for (int r = 0; r < 4; ++r) ps[r] += __shfl_xor(ps[r], m);
      }
      if (l16 == 0) *(f32x4*)&pve[(b * 64 + j0 + jc) * 128 + c0[nt]] = ps;
    }
  }
  bar_lgkm();
  if (!LAST) {
#pragma unroll
    for (int t = 0; t < 8; ++t) {
      int idx = tid + t * 256;
      *(int4*)&ebase[idx * 8] =
          *(const int4*)&As[idx >> 10][(idx >> 4) & 63][(idx & 15) * 8];
    }
  } else {
    const int i = tid >> 2, q = tid & 3;
#pragma unroll
    for (int jc = 0; jc < 2; ++jc) {
      float d = 0.f;
#pragma unroll
      for (int t = 0; t < 4; ++t) {
        bf16x8 x = *(const bf16x8*)&As[jc][i][q * 32 + t * 8];
#pragma unroll
        for (int u = 0; u < 8; ++u) d += (float)x[u] * W3s[q * 32 + t * 8 + u];
      }
      d += __shfl_xor(d, 1);
      d += __shfl_xor(d, 2);
      if (q == 0) edt[(b * 64 + j0 + jc) * 64 + i] = d;
    }
  }
}

// ------------- inner v pass + BN-affine on v + rawev for next layer -------------
// v_norm = sc_n*v_raw + sh_n (prev layer's BN; identity for l=0).
// v_next = relu(concat(pve, v_norm)@vW + vb) + v_norm  -> written raw (pre-BN_l).
__global__ __launch_bounds__(256) void k_v_inner(const float* __restrict__ pve,
    float* __restrict__ v, const float* __restrict__ vW,
    const float* __restrict__ vb, float* __restrict__ stats,
    const float* __restrict__ stats_prev, const float* __restrict__ g_prev,
    const float* __restrict__ bt_prev, const float* __restrict__ evW_next,
    float* __restrict__ rawev) {
  __shared__ float in_s[8][256];
  __shared__ float outs[8][132];  // +4 pad
  __shared__ float part[16][2];
  __shared__ float scb[8], shb[8];
  const int r0 = blockIdx.x * 8;
  const int tid = threadIdx.x;
  const int c = tid & 127, h = tid >> 7;
  if (tid < 8) {  // per-row BN affine of the PREVIOUS layer
    int n = (r0 + tid) & 63;
    if (stats_prev) {
      float mu = stats_prev[n] * (1.f / 8192.f);
      float var = stats_prev[64 + n] * (1.f / 8192.f) - mu * mu;
      float sc = rsqrtf(var + 128.f) * g_prev[n];
      scb[tid] = sc;
      shb[tid] = bt_prev[n] - mu * sc;
    } else {
      scb[tid] = 1.f;
      shb[tid] = 0.f;
    }
  }
  __syncthreads();
#pragma unroll
  for (int u = 0; u < 4; ++u) {
    int idx = u * 256 + tid;
    int rr = idx >> 7, k = idx & 127;
    in_s[rr][k] = pve[(r0 + rr) * 128 + k];
    in_s[rr][128 + k] = v[(r0 + rr) * 128 + k] * scb[rr] + shb[rr];  // v_norm
  }
  __syncthreads();
  float acc[4];
  const float bv = vb[c];
#pragma unroll
  for (int r = 0; r < 4; ++r) acc[r] = bv;
  for (int k4 = 0; k4 < 256; k4 += 4) {
    float w0 = vW[(k4 + 0) * 128 + c], w1 = vW[(k4 + 1) * 128 + c];
    float w2 = vW[(k4 + 2) * 128 + c], w3 = vW[(k4 + 3) * 128 + c];
#pragma unroll
    for (int r = 0; r < 4; ++r) {
      float4 x = *(const float4*)&in_s[h * 4 + r][k4];
      acc[r] += x.x * w0 + x.y * w1 + x.z * w2 + x.w * w3;
    }
  }
#pragma unroll
  for (int r = 0; r < 4; ++r) {
    // relu + residual with NORMALIZED v; result is raw (pre-BN of this layer)
    float val = fmaxf(acc[r], 0.f) + in_s[h * 4 + r][128 + c];
    outs[h * 4 + r][c] = val;
    v[(r0 + h * 4 + r) * 128 + c] = val;
  }
  __syncthreads();
  if (evW_next) {  // rawev = v_raw_new @ evW_next (no bias, pre-BN)
    float acc2[4] = {0.f, 0.f, 0.f, 0.f};
    for (int k4 = 0; k4 < 128; k4 += 4) {
      float w0 = evW_next[(k4 + 0) * 128 + c], w1 = evW_next[(k4 + 1) * 128 + c];
      float w2 = evW_next[(k4 + 2) * 128 + c], w3 = evW_next[(k4 + 3) * 128 + c];
#pragma unroll
      for (int r = 0; r < 4; ++r) {
        float4 x = *(const float4*)&outs[h * 4 + r][k4];
        acc2[r] += x.x * w0 + x.y * w1 + x.z * w2 + x.w * w3;
      }
    }
#pragma unroll
    for (int r = 0; r < 4; ++r) rawev[(r0 + h * 4 + r) * 128 + c] = acc2[r];
  }
  if (tid < 16) {  // BN stats of THIS layer, on raw v_new
    int rr = tid >> 1, half = tid & 1;
    float s = 0.f, s2 = 0.f;
    for (int k = 0; k < 64; ++k) {
      float x = outs[rr][half * 64 + k];
      s += x; s2 += x * x;
    }
    part[tid][0] = s;
    part[tid][1] = s2;
  }
  __syncthreads();
  if (tid < 8) {
    int n = (r0 + tid) & 63;
    atomicAdd(&stats[n], part[tid * 2][0] + part[tid * 2 + 1][0]);
    atomicAdd(&stats[64 + n], part[tid * 2][1] + part[tid * 2 + 1][1]);
  }
}

// ------------- g3 final: per-b block -------------
__global__ __launch_bounds__(256) void k_g3(const float* __restrict__ vv,
    const float* __restrict__ stats3, const float* __restrict__ g,
    const float* __restrict__ bt, const float* __restrict__ evW3,
    const float* __restrict__ evb3, const float* __restrict__ eb3,
    const float* __restrict__ edt, const float* __restrict__ vW3,
    const float* __restrict__ vb3, float* __restrict__ out_v,
    float* __restrict__ out_e) {
  __shared__ float vbn[64][132];
  __shared__ float edts[64][68];
  __shared__ float scs[64], shs[64];
  __shared__ float W3e[128];
  __shared__ float vWs[132];
  __shared__ float ev3s[64];
  __shared__ float pj[4][64];
  const int b = blockIdx.x, tid = threadIdx.x;
  if (tid < 64) {
    float mu = stats3[tid] * (1.f / 8192.f);
    float var = stats3[64 + tid] * (1.f / 8192.f) - mu * mu;
    float sc = rsqrtf(var + 128.f) * g[tid];
    scs[tid] = sc;
    shs[tid] = bt[tid] - mu * sc;
  }
  if (tid < 128) W3e[tid] = evW3[tid];
  if (tid < 129) vWs[tid] = vW3[tid];
  __syncthreads();
#pragma unroll
  for (int t = 0; t < 8; ++t) {
    int idx = t * 1024 + tid * 4;
    int row = idx >> 7, cc = idx & 127;
    f32x4 x = *(const f32x4*)&vv[(b * 64 + row) * 128 + cc];
    *(f32x4*)&vbn[row][cc] = x * scs[row] + shs[row];
  }
#pragma unroll
  for (int t = 0; t < 4; ++t) {
    int idx = t * 1024 + tid * 4;
    int j = idx >> 6, i = idx & 63;
    *(f32x4*)&edts[j][i] = *(const f32x4*)&edt[(b * 64 + j) * 64 + i];
  }
  __syncthreads();
  {
    int i = tid >> 2, q = tid & 3;
    float d = 0.f;
#pragma unroll
    for (int u = 0; u < 32; ++u) d += vbn[i][q * 32 + u] * W3e[q * 32 + u];
    d += __shfl_xor(d, 1);
    d += __shfl_xor(d, 2);
    if (q == 0) ev3s[i] = d + evb3[0];
  }
  __syncthreads();
  {
    int q = tid >> 6, j = tid & 63;
    float s = 0.f;
    const float e3 = eb3[0];
    const float evj = ev3s[j];
#pragma unroll
    for (int r = 0; r < 16; ++r) {
      int i = q * 16 + r;
      float val = edts[j][i] + e3 + ev3s[i] + evj;
      out_e[(b * 64 + i) * 64 + j] = val;
      s += val;
    }
    pj[q][j] = s;
  }
  __syncthreads();
  {
    int n = tid >> 2, q = tid & 3;
    float d = 0.f;
#pragma unroll
    for (int u = 0; u < 32; ++u) d += vbn[n][q * 32 + u] * vWs[1 + q * 32 + u];
    d += __shfl_xor(d, 1);
    d += __shfl_xor(d, 2);
    if (q == 0) {
      float p3 = pj[0][n] + pj[1][n] + pj[2][n] + pj[3][n];
      out_v[b * 64 + n] = d + p3 * vWs[0] + vb3[0];
    }
  }
}

extern "C" void kernel_launch(void* const* d_in, const int* in_sizes, int n_in,
                              void* d_out, int out_size, void* d_ws, size_t ws_size,
                              hipStream_t stream) {
  const float* in_v    = (const float*)d_in[0];
  const float* in_e    = (const float*)d_in[1];
  const float* bn_in_g = (const float*)d_in[2];
  const float* bn_in_b = (const float*)d_in[3];
  const float* g1_evW  = (const float*)d_in[4];
  const float* g1_evb  = (const float*)d_in[5];
  const float* g1_eW   = (const float*)d_in[6];
  const float* g1_eb   = (const float*)d_in[7];
  const float* g1_vW   = (const float*)d_in[8];
  const float* g1_vb   = (const float*)d_in[9];
  const float* inn_evW = (const float*)d_in[10];
  const float* inn_evb = (const float*)d_in[11];
  const float* inn_eW  = (const float*)d_in[12];
  const float* inn_eb  = (const float*)d_in[13];
  const float* inn_vW  = (const float*)d_in[14];
  const float* inn_vb  = (const float*)d_in[15];
  const float* bn_g    = (const float*)d_in[16];
  const float* bn_b    = (const float*)d_in[17];
  const float* g3_evW  = (const float*)d_in[18];
  const float* g3_evb  = (const float*)d_in[19];
  const float* g3_eW   = (const float*)d_in[20];
  const float* g3_eb   = (const float*)d_in[21];
  const float* g3_vW   = (const float*)d_in[22];
  const float* g3_vb   = (const float*)d_in[23];

  char* ws = (char*)d_ws;
  bf16_t* e_ws  = (bf16_t*)(ws);                      // 64MB : e_t[b][j][i][c] bf16
  float* v      = (float*)(ws + 67108864);            // 2MB : RAW (pre-BN) v
  float* ev     = (float*)(ws + 69206016);            // 2MB : rawev (pre-BN, no bias)
  float* pve    = (float*)(ws + 71303168);            // 2MB
  float* ev_g1  = (float*)(ws + 73400320);            // 2MB : g1 ev (with bias)
  float* v0     = (float*)(ws + 75497472);            // 512KB
  bf16_t* Wt    = (bf16_t*)(ws + 76021760);           // 128KB
  float* edt    = (float*)(ws + 76152832);            // 1MB : edot[b][j][i]
  float* stats  = (float*)(ws + 77201408);            // 2KB (4 layers x 128 f32)
  float* colsum = (float*)(ws + 77203456);            // 2KB (4 layers x 128 f32)

  float* out_v = (float*)d_out;          // [B,N,1] = 4096
  float* out_e = (float*)d_out + 4096;   // [B,N,N,1] = 262144

  k_prep<<<321, 256, 0, stream>>>(in_v, bn_in_g, bn_in_b, inn_eW, inn_evW,
                                  v0, Wt, stats, colsum);

  // ---- g1 ----
  k_ev32<<<512, 256, 0, stream>>>(v0, g1_evW, g1_evb, ev_g1);
  k_edge_g1<<<2048, 256, 0, stream>>>(in_e, g1_eW, g1_eb, ev_g1, e_ws, pve);
  k_vg1_ev<<<512, 256, 0, stream>>>(pve, v0, g1_vW, g1_vb, inn_evW, v, ev);

  // ---- inner layers (BN folded; evbn kernels gone) ----
  for (int l = 0; l < 4; ++l) {
    const float* sp = (l > 0) ? stats + (l - 1) * 128 : nullptr;
    const float* gp = bn_g + (l > 0 ? (l - 1) * 64 : 0);
    const float* bp = bn_b + (l > 0 ? (l - 1) * 64 : 0);
    if (l < 3)
      k_edge_inner<false><<<2048, 256, 0, stream>>>(e_ws, Wt + l * 16384,
          inn_eb + l * 128, inn_evb + l * 128, ev, colsum + l * 128,
          sp, gp, bp, pve, g3_eW, edt);
    else
      k_edge_inner<true><<<2048, 256, 0, stream>>>(e_ws, Wt + l * 16384,
          inn_eb + l * 128, inn_evb + l * 128, ev, colsum + l * 128,
          sp, gp, bp, pve, g3_eW, edt);
    k_v_inner<<<512, 256, 0, stream>>>(pve, v, inn_vW + l * 32768, inn_vb + l * 128,
                                       stats + l * 128, sp, gp, bp,
                                       (l < 3) ? inn_evW + (l + 1) * 16384 : nullptr,
                                       ev);
  }

  // ---- g3 final (BN of layer 3 on the fly; pve3 in-block) ----
  k_g3<<<64, 256, 0, stream>>>(v, stats + 384, bn_g + 192, bn_b + 192,
                               g3_evW, g3_evb, g3_eb, edt, g3_vW, g3_vb,
                               out_v, out_e);
}